// Round 1
// baseline (2239.504 us; speedup 1.0000x reference)
//
#include <hip/hip_runtime.h>
#include <hip/hip_bf16.h>

// GCN 3-layer embedder: h = relu(Agg(xW1)+b1); relu(Agg(hW2)+b2); Agg(hW3)+b3; mean over nodes.
// Agg(t)[i] = sum_{e: dst=i} t[src_e]*dinv[src]*dinv[dst]  +  t[i]*dinv[i]^2  (self loop)
// deg[i] = in-degree(i) + 1 (self loop), dinv = rsqrt(deg).

#define C 128          // channels (in=hid=out=128)
#define C4 32          // channels as float4

// ---------------- degree ----------------
__global__ __launch_bounds__(256) void deg_kernel(const int* __restrict__ ei, int E,
                                                  float* __restrict__ deg) {
    int i = blockIdx.x * 256 + threadIdx.x;
    if (i < E) unsafeAtomicAdd(&deg[ei[E + i]], 1.0f);
}

__global__ __launch_bounds__(256) void dinv_kernel(float* __restrict__ d, int N) {
    int i = blockIdx.x * 256 + threadIdx.x;
    if (i < N) d[i] = rsqrtf(d[i] + 1.0f);   // +1 = self loop
}

// ---------------- GEMM: T[M x 128] = A[M x 128] @ W[128 x 128] ----------------
// 64-row tile per block, 256 threads. Xs = 32KB, Wsh = 32KB (two 64-k-row halves).
__global__ __launch_bounds__(256) void gemm128(const float* __restrict__ A,
                                               const float* __restrict__ W,
                                               float* __restrict__ T, int M) {
    __shared__ float Xs[64 * C];    // 32 KB
    __shared__ float Wsh[64 * C];   // 32 KB
    const int t = threadIdx.x;
    const int row0 = blockIdx.x * 64;

    const float4* A4 = (const float4*)A;
    float4* Xs4 = (float4*)Xs;
#pragma unroll
    for (int i = 0; i < 8; ++i) {
        int idx = t + i * 256;          // float4 index in 64x32 tile
        int r = idx >> 5;
        int gr = row0 + r;
        Xs4[idx] = (gr < M) ? A4[(size_t)gr * C4 + (idx & 31)]
                            : make_float4(0.f, 0.f, 0.f, 0.f);
    }

    const int cg = t & 31;   // 4-col group
    const int rg = t >> 5;   // 8-row group (rows rg*8 .. rg*8+7)
    float4 acc[8];
#pragma unroll
    for (int i = 0; i < 8; ++i) acc[i] = make_float4(0.f, 0.f, 0.f, 0.f);

    const float4* W4 = (const float4*)W;
    float4* Ws4 = (float4*)Wsh;

    for (int kk = 0; kk < 2; ++kk) {
        __syncthreads();                       // Xs ready (kk=0) / prev compute done (kk=1)
#pragma unroll
        for (int i = 0; i < 8; ++i) {
            int idx = t + i * 256;             // 2048 float4 = 64 k-rows x 32
            Ws4[idx] = W4[kk * 2048 + idx];
        }
        __syncthreads();
#pragma unroll
        for (int k4 = 0; k4 < 16; ++k4) {
            float4 w0 = Ws4[(k4 * 4 + 0) * C4 + cg];
            float4 w1 = Ws4[(k4 * 4 + 1) * C4 + cg];
            float4 w2 = Ws4[(k4 * 4 + 2) * C4 + cg];
            float4 w3 = Ws4[(k4 * 4 + 3) * C4 + cg];
#pragma unroll
            for (int i = 0; i < 8; ++i) {
                float4 xv = Xs4[(rg * 8 + i) * C4 + kk * 16 + k4];
                acc[i].x = fmaf(xv.x, w0.x, fmaf(xv.y, w1.x, fmaf(xv.z, w2.x, fmaf(xv.w, w3.x, acc[i].x))));
                acc[i].y = fmaf(xv.x, w0.y, fmaf(xv.y, w1.y, fmaf(xv.z, w2.y, fmaf(xv.w, w3.y, acc[i].y))));
                acc[i].z = fmaf(xv.x, w0.z, fmaf(xv.y, w1.z, fmaf(xv.z, w2.z, fmaf(xv.w, w3.z, acc[i].z))));
                acc[i].w = fmaf(xv.x, w0.w, fmaf(xv.y, w1.w, fmaf(xv.z, w2.w, fmaf(xv.w, w3.w, acc[i].w))));
            }
        }
    }

    float4* T4 = (float4*)T;
#pragma unroll
    for (int i = 0; i < 8; ++i) {
        int gr = row0 + rg * 8 + i;
        if (gr < M) T4[(size_t)gr * C4 + cg] = acc[i];
    }
}

// ---------------- edge scatter: agg[dst] += t[src] * dinv[src]*dinv[dst] ----------------
// One wavefront (64 lanes) per edge; lane handles 2 channels (float2 gather, 2 f32 atomics).
__global__ __launch_bounds__(256) void scatter_edges(const int* __restrict__ ei, int E,
                                                     const float* __restrict__ t,
                                                     const float* __restrict__ dinv,
                                                     float* __restrict__ agg) {
    int tid = blockIdx.x * 256 + threadIdx.x;
    int e = tid >> 6;
    if (e >= E) return;
    int lane = tid & 63;
    int src = ei[e];
    int dst = ei[E + e];
    float n = dinv[src] * dinv[dst];
    float2 v = ((const float2*)t)[(size_t)src * 64 + lane];
    float* dp = agg + (size_t)dst * C + lane * 2;
    unsafeAtomicAdd(dp, v.x * n);
    unsafeAtomicAdd(dp + 1, v.y * n);
}

// ---------------- epilogue: h = relu(agg + t*dinv^2 + b), in place over agg ----------------
__global__ __launch_bounds__(256) void epilogue_relu(float* __restrict__ hb,
                                                     const float* __restrict__ t,
                                                     const float* __restrict__ dinv,
                                                     const float* __restrict__ b, int N) {
    int idx = blockIdx.x * 256 + threadIdx.x;   // float4 index
    if (idx >= N * C4) return;
    int node = idx >> 5;
    int cg = idx & 31;
    float di = dinv[node];
    float s = di * di;
    float4 a = ((float4*)hb)[idx];
    float4 tv = ((const float4*)t)[idx];
    float4 bv = ((const float4*)b)[cg];
    a.x = fmaxf(fmaf(tv.x, s, a.x) + bv.x, 0.f);
    a.y = fmaxf(fmaf(tv.y, s, a.y) + bv.y, 0.f);
    a.z = fmaxf(fmaf(tv.z, s, a.z) + bv.z, 0.f);
    a.w = fmaxf(fmaf(tv.w, s, a.w) + bv.w, 0.f);
    ((float4*)hb)[idx] = a;
}

// ---------------- final: out[c] = mean_i(agg + t*dinv^2)[i][c] + b[c] ----------------
__global__ __launch_bounds__(128) void final_reduce(const float* __restrict__ agg,
                                                    const float* __restrict__ t,
                                                    const float* __restrict__ dinv,
                                                    const float* __restrict__ b,
                                                    float* __restrict__ out,
                                                    int N, int npb) {
    int c = threadIdx.x;   // 0..127
    int i0 = blockIdx.x * npb;
    int i1 = min(i0 + npb, N);
    float s = 0.f;
    for (int i = i0; i < i1; ++i) {
        float di = dinv[i];
        s += fmaf(t[(size_t)i * C + c], di * di, agg[(size_t)i * C + c]);
    }
    s *= (1.0f / N);
    if (blockIdx.x == 0) s += b[c];
    unsafeAtomicAdd(&out[c], s);
}

extern "C" void kernel_launch(void* const* d_in, const int* in_sizes, int n_in,
                              void* d_out, int out_size, void* d_ws, size_t ws_size,
                              hipStream_t stream) {
    const float* x  = (const float*)d_in[0];
    const int*   ei = (const int*)d_in[1];
    const float* W1 = (const float*)d_in[2];
    const float* b1 = (const float*)d_in[3];
    const float* W2 = (const float*)d_in[4];
    const float* b2 = (const float*)d_in[5];
    const float* W3 = (const float*)d_in[6];
    const float* b3 = (const float*)d_in[7];
    float* out = (float*)d_out;

    const int N = in_sizes[0] / C;      // 50000
    const int E = in_sizes[1] / 2;      // 800000

    const size_t hbytes = (size_t)N * C * sizeof(float);   // 25.6 MB
    char* ws = (char*)d_ws;
    float* buf0 = (float*)ws;                    // t = h @ W
    float* buf1 = (float*)(ws + hbytes);         // agg / h
    float* dinv = (float*)(ws + 2 * hbytes);     // deg -> dinv

    hipMemsetAsync(dinv, 0, (size_t)N * sizeof(float), stream);
    hipMemsetAsync(out, 0, (size_t)C * sizeof(float), stream);

    deg_kernel<<<(E + 255) / 256, 256, 0, stream>>>(ei, E, dinv);
    dinv_kernel<<<(N + 255) / 256, 256, 0, stream>>>(dinv, N);

    const int gb = (N + 63) / 64;
    const int sb = (int)(((long long)E * 64 + 255) / 256);
    const int eb = (N * C4 + 255) / 256;
    const int rb = 391;
    const int npb = (N + rb - 1) / rb;

    // layer 1
    gemm128<<<gb, 256, 0, stream>>>(x, W1, buf0, N);
    hipMemsetAsync(buf1, 0, hbytes, stream);
    scatter_edges<<<sb, 256, 0, stream>>>(ei, E, buf0, dinv, buf1);
    epilogue_relu<<<eb, 256, 0, stream>>>(buf1, buf0, dinv, b1, N);

    // layer 2
    gemm128<<<gb, 256, 0, stream>>>(buf1, W2, buf0, N);
    hipMemsetAsync(buf1, 0, hbytes, stream);
    scatter_edges<<<sb, 256, 0, stream>>>(ei, E, buf0, dinv, buf1);
    epilogue_relu<<<eb, 256, 0, stream>>>(buf1, buf0, dinv, b2, N);

    // layer 3
    gemm128<<<gb, 256, 0, stream>>>(buf1, W3, buf0, N);
    hipMemsetAsync(buf1, 0, hbytes, stream);
    scatter_edges<<<sb, 256, 0, stream>>>(ei, E, buf0, dinv, buf1);
    final_reduce<<<rb, C, 0, stream>>>(buf1, buf0, dinv, b3, out, N, npb);
}

// Round 2
// 495.569 us; speedup vs baseline: 4.5191x; 4.5191x over previous
//
#include <hip/hip_runtime.h>
#include <hip/hip_bf16.h>

// GCN 3-layer embedder, CSR-gather formulation (no float atomics on the feature path).
// Agg(t)[i] = sum_{e: dst=i} t[src_e]*dinv[src]*dinv[dst] + t[i]*dinv[i]^2
// Layer 3 + mean is algebraically collapsed:
//   out = ((sum_i w_i * h2[i]) @ W3)/N + b3,  w_i = dinv_i^2 + dinv_i * sum_{e:src=i} dinv[dst_e]

#define C 128
#define C4 32

// ---------------- degree count (int atomics) ----------------
__global__ __launch_bounds__(256) void deg_count(const int* __restrict__ ei, int E,
                                                 int* __restrict__ cnt) {
    int i = blockIdx.x * 256 + threadIdx.x;
    if (i < E) atomicAdd(&cnt[ei[E + i]], 1);
}

__global__ __launch_bounds__(256) void dinv_kernel(const int* __restrict__ cnt,
                                                   float* __restrict__ d, int N) {
    int i = blockIdx.x * 256 + threadIdx.x;
    if (i < N) d[i] = rsqrtf((float)cnt[i] + 1.0f);   // +1 = self loop
}

// ---------------- exclusive scan over cnt -> rowptr, cursor (single block) ----------------
__global__ __launch_bounds__(1024) void scan_kernel(const int* __restrict__ cnt,
                                                    int* __restrict__ rowptr,
                                                    int* __restrict__ cursor, int N) {
    __shared__ int part[1024];
    const int t = threadIdx.x;
    const int chunk = (N + 1023) / 1024;
    const int beg = t * chunk, end = min(beg + chunk, N);
    int s = 0;
    for (int i = beg; i < end; ++i) s += cnt[i];
    part[t] = s;
    __syncthreads();
    for (int off = 1; off < 1024; off <<= 1) {
        int v = (t >= off) ? part[t - off] : 0;
        __syncthreads();
        part[t] += v;
        __syncthreads();
    }
    int base = (t > 0) ? part[t - 1] : 0;
    for (int i = beg; i < end; ++i) {
        rowptr[i] = base; cursor[i] = base; base += cnt[i];
    }
    if (t == 1023) rowptr[N] = part[1023];
}

// ---------------- CSR fill + per-src norm-weight accumulation ----------------
__global__ __launch_bounds__(256) void fill_csr(const int* __restrict__ ei, int E,
                                                const float* __restrict__ dinv,
                                                int* __restrict__ cursor,
                                                int2* __restrict__ csr,
                                                float* __restrict__ srcw) {
    int e = blockIdx.x * 256 + threadIdx.x;
    if (e >= E) return;
    int src = ei[e];
    int dst = ei[E + e];
    float nrm = dinv[src] * dinv[dst];
    int pos = atomicAdd(&cursor[dst], 1);
    csr[pos] = make_int2(src, __float_as_int(nrm));
    unsafeAtomicAdd(&srcw[src], dinv[dst]);
}

// ---------------- GEMM: T[M x 128] = A[M x 128] @ W[128 x 128] ----------------
__global__ __launch_bounds__(256) void gemm128(const float* __restrict__ A,
                                               const float* __restrict__ W,
                                               float* __restrict__ T, int M) {
    __shared__ float Xs[64 * C];
    __shared__ float Wsh[64 * C];
    const int t = threadIdx.x;
    const int row0 = blockIdx.x * 64;

    const float4* A4 = (const float4*)A;
    float4* Xs4 = (float4*)Xs;
#pragma unroll
    for (int i = 0; i < 8; ++i) {
        int idx = t + i * 256;
        int r = idx >> 5;
        int gr = row0 + r;
        Xs4[idx] = (gr < M) ? A4[(size_t)gr * C4 + (idx & 31)]
                            : make_float4(0.f, 0.f, 0.f, 0.f);
    }

    const int cg = t & 31;
    const int rg = t >> 5;
    float4 acc[8];
#pragma unroll
    for (int i = 0; i < 8; ++i) acc[i] = make_float4(0.f, 0.f, 0.f, 0.f);

    const float4* W4 = (const float4*)W;
    float4* Ws4 = (float4*)Wsh;

    for (int kk = 0; kk < 2; ++kk) {
        __syncthreads();
#pragma unroll
        for (int i = 0; i < 8; ++i) {
            int idx = t + i * 256;
            Ws4[idx] = W4[kk * 2048 + idx];
        }
        __syncthreads();
#pragma unroll
        for (int k4 = 0; k4 < 16; ++k4) {
            float4 w0 = Ws4[(k4 * 4 + 0) * C4 + cg];
            float4 w1 = Ws4[(k4 * 4 + 1) * C4 + cg];
            float4 w2 = Ws4[(k4 * 4 + 2) * C4 + cg];
            float4 w3 = Ws4[(k4 * 4 + 3) * C4 + cg];
#pragma unroll
            for (int i = 0; i < 8; ++i) {
                float4 xv = Xs4[(rg * 8 + i) * C4 + kk * 16 + k4];
                acc[i].x = fmaf(xv.x, w0.x, fmaf(xv.y, w1.x, fmaf(xv.z, w2.x, fmaf(xv.w, w3.x, acc[i].x))));
                acc[i].y = fmaf(xv.x, w0.y, fmaf(xv.y, w1.y, fmaf(xv.z, w2.y, fmaf(xv.w, w3.y, acc[i].y))));
                acc[i].z = fmaf(xv.x, w0.z, fmaf(xv.y, w1.z, fmaf(xv.z, w2.z, fmaf(xv.w, w3.z, acc[i].z))));
                acc[i].w = fmaf(xv.x, w0.w, fmaf(xv.y, w1.w, fmaf(xv.z, w2.w, fmaf(xv.w, w3.w, acc[i].w))));
            }
        }
    }

    float4* T4 = (float4*)T;
#pragma unroll
    for (int i = 0; i < 8; ++i) {
        int gr = row0 + rg * 8 + i;
        if (gr < M) T4[(size_t)gr * C4 + cg] = acc[i];
    }
}

// ---------------- CSR aggregate, fused self-loop + bias + relu ----------------
// One wave per dst node; lane = 2 channels (float2).
__global__ __launch_bounds__(256) void agg_kernel(const int* __restrict__ rowptr,
                                                  const int2* __restrict__ csr,
                                                  const float* __restrict__ t,
                                                  const float* __restrict__ dinv,
                                                  const float* __restrict__ b,
                                                  float* __restrict__ h, int N) {
    int tid = blockIdx.x * 256 + threadIdx.x;
    int node = tid >> 6;
    if (node >= N) return;
    int lane = tid & 63;
    int beg = rowptr[node];
    int end = rowptr[node + 1];

    const float2* t2 = (const float2*)t;
    float2 acc = make_float2(0.f, 0.f);

    int k = beg;
    for (; k + 1 < end; k += 2) {
        int2 p0 = csr[k];
        int2 p1 = csr[k + 1];
        float2 v0 = t2[(size_t)p0.x * 64 + lane];
        float2 v1 = t2[(size_t)p1.x * 64 + lane];
        float n0 = __int_as_float(p0.y);
        float n1 = __int_as_float(p1.y);
        acc.x = fmaf(v0.x, n0, acc.x);
        acc.y = fmaf(v0.y, n0, acc.y);
        acc.x = fmaf(v1.x, n1, acc.x);
        acc.y = fmaf(v1.y, n1, acc.y);
    }
    if (k < end) {
        int2 p0 = csr[k];
        float2 v0 = t2[(size_t)p0.x * 64 + lane];
        float n0 = __int_as_float(p0.y);
        acc.x = fmaf(v0.x, n0, acc.x);
        acc.y = fmaf(v0.y, n0, acc.y);
    }

    float di = dinv[node];
    float s = di * di;
    float2 tv = t2[(size_t)node * 64 + lane];
    float2 bv = ((const float2*)b)[lane];
    acc.x = fmaxf(fmaf(tv.x, s, acc.x) + bv.x, 0.f);
    acc.y = fmaxf(fmaf(tv.y, s, acc.y) + bv.y, 0.f);
    ((float2*)h)[(size_t)node * 64 + lane] = acc;
}

// ---------------- weighted row-sum: v[c] = sum_i w_i * h[i][c] ----------------
__global__ __launch_bounds__(128) void wreduce(const float* __restrict__ h,
                                               const float* __restrict__ dinv,
                                               const float* __restrict__ srcw,
                                               float* __restrict__ v, int N, int npb) {
    int c = threadIdx.x;
    int i0 = blockIdx.x * npb;
    int i1 = min(i0 + npb, N);
    float s = 0.f;
    for (int i = i0; i < i1; ++i) {
        float di = dinv[i];
        float w = di * (di + srcw[i]);
        s = fmaf(h[(size_t)i * C + c], w, s);
    }
    unsafeAtomicAdd(&v[c], s);
}

// ---------------- out = (v @ W3)/N + b3 ----------------
__global__ __launch_bounds__(128) void matvec(const float* __restrict__ v,
                                              const float* __restrict__ W,
                                              const float* __restrict__ b,
                                              float* __restrict__ out, float invN) {
    int c = threadIdx.x;
    float s = 0.f;
    for (int k = 0; k < C; ++k) s = fmaf(v[k], W[(size_t)k * C + c], s);
    out[c] = s * invN + b[c];
}

extern "C" void kernel_launch(void* const* d_in, const int* in_sizes, int n_in,
                              void* d_out, int out_size, void* d_ws, size_t ws_size,
                              hipStream_t stream) {
    const float* x  = (const float*)d_in[0];
    const int*   ei = (const int*)d_in[1];
    const float* W1 = (const float*)d_in[2];
    const float* b1 = (const float*)d_in[3];
    const float* W2 = (const float*)d_in[4];
    const float* b2 = (const float*)d_in[5];
    const float* W3 = (const float*)d_in[6];
    const float* b3 = (const float*)d_in[7];
    float* out = (float*)d_out;

    const int N = in_sizes[0] / C;      // 50000
    const int E = in_sizes[1] / 2;      // 800000

    const size_t hbytes = (size_t)N * C * sizeof(float);   // 25.6 MB
    char* ws = (char*)d_ws;
    size_t off = 0;
    auto alloc = [&](size_t bytes) { char* p = ws + off; off += (bytes + 255) & ~(size_t)255; return p; };
    float* buf0   = (float*)alloc(hbytes);                    // t = h @ W
    float* buf1   = (float*)alloc(hbytes);                    // h
    int2*  csr    = (int2*)alloc((size_t)E * sizeof(int2));   // 6.4 MB
    int*   rowptr = (int*)alloc((size_t)(N + 1) * sizeof(int));
    int*   cursor = (int*)alloc((size_t)N * sizeof(int));
    int*   cnt    = (int*)alloc((size_t)N * sizeof(int));
    float* dinv   = (float*)alloc((size_t)N * sizeof(float));
    float* srcw   = (float*)alloc((size_t)N * sizeof(float));
    float* vsum   = (float*)alloc((size_t)C * sizeof(float));

    hipMemsetAsync(cnt, 0, (size_t)N * sizeof(int), stream);
    hipMemsetAsync(srcw, 0, (size_t)N * sizeof(float), stream);
    hipMemsetAsync(vsum, 0, (size_t)C * sizeof(float), stream);

    const int ebl = (E + 255) / 256;
    deg_count<<<ebl, 256, 0, stream>>>(ei, E, cnt);
    dinv_kernel<<<(N + 255) / 256, 256, 0, stream>>>(cnt, dinv, N);
    scan_kernel<<<1, 1024, 0, stream>>>(cnt, rowptr, cursor, N);
    fill_csr<<<ebl, 256, 0, stream>>>(ei, E, dinv, cursor, csr, srcw);

    const int gb = (N + 63) / 64;
    const int ab = (int)(((long long)N * 64 + 255) / 256);
    const int rb = 391;
    const int npb = (N + rb - 1) / rb;

    // layer 1
    gemm128<<<gb, 256, 0, stream>>>(x, W1, buf0, N);
    agg_kernel<<<ab, 256, 0, stream>>>(rowptr, csr, buf0, dinv, b1, buf1, N);
    // layer 2
    gemm128<<<gb, 256, 0, stream>>>(buf1, W2, buf0, N);
    agg_kernel<<<ab, 256, 0, stream>>>(rowptr, csr, buf0, dinv, b2, buf1, N);
    // layer 3 collapsed: out = ((sum_i w_i h2[i]) @ W3)/N + b3
    wreduce<<<rb, 128, 0, stream>>>(buf1, dinv, srcw, vsum, N, npb);
    matvec<<<1, 128, 0, stream>>>(vsum, W3, b3, out, 1.0f / (float)N);
}

// Round 3
// 404.485 us; speedup vs baseline: 5.5367x; 1.2252x over previous
//
#include <hip/hip_runtime.h>
#include <hip/hip_bf16.h>

// GCN 3-layer embedder, CSR-gather formulation (no float atomics on the feature path).
// Agg(t)[i] = sum_{e: dst=i} t[src_e]*dinv[src]*dinv[dst] + t[i]*dinv[i]^2
// Layer 3 + mean is algebraically collapsed:
//   out = ((sum_i w_i * h2[i]) @ W3)/N + b3,  w_i = dinv_i^2 + dinv_i * sum_{e:src=i} dinv[dst_e]

#define C 128
#define C4 32
#define SCHUNK 4096   // nodes per scan block (256 threads x 16)

// ---------------- degree count (int atomics) ----------------
__global__ __launch_bounds__(256) void deg_count(const int* __restrict__ ei, int E,
                                                 int* __restrict__ cnt) {
    int i = blockIdx.x * 256 + threadIdx.x;
    if (i < E) atomicAdd(&cnt[ei[E + i]], 1);
}

__global__ __launch_bounds__(256) void dinv_kernel(const int* __restrict__ cnt,
                                                   float* __restrict__ d, int N) {
    int i = blockIdx.x * 256 + threadIdx.x;
    if (i < N) d[i] = rsqrtf((float)cnt[i] + 1.0f);   // +1 = self loop
}

// ---------------- hierarchical exclusive scan: cnt -> rowptr, cursor ----------------
// stage 1: per-block sums
__global__ __launch_bounds__(256) void scan_part(const int* __restrict__ cnt,
                                                 int* __restrict__ bsum, int N) {
    __shared__ int sh[256];
    const int t = threadIdx.x;
    int base = blockIdx.x * SCHUNK + t * 16;
    int s = 0;
#pragma unroll
    for (int i = 0; i < 16; ++i) {
        int idx = base + i;
        if (idx < N) s += cnt[idx];
    }
    sh[t] = s;
    __syncthreads();
    for (int off = 128; off > 0; off >>= 1) {
        if (t < off) sh[t] += sh[t + off];
        __syncthreads();
    }
    if (t == 0) bsum[blockIdx.x] = sh[0];
}

// stage 2: exclusive scan of block sums (nb is tiny, ~13)
__global__ void scan_top(int* __restrict__ bsum, int nb) {
    if (threadIdx.x == 0) {
        int run = 0;
        for (int i = 0; i < nb; ++i) { int v = bsum[i]; bsum[i] = run; run += v; }
    }
}

// stage 3: write rowptr & cursor with offsets
__global__ __launch_bounds__(256) void scan_write(const int* __restrict__ cnt,
                                                  const int* __restrict__ bsum,
                                                  int* __restrict__ rowptr,
                                                  int* __restrict__ cursor, int N) {
    __shared__ int sh[256];
    const int t = threadIdx.x;
    int base = blockIdx.x * SCHUNK + t * 16;
    int local[16];
    int s = 0;
#pragma unroll
    for (int i = 0; i < 16; ++i) {
        int idx = base + i;
        int v = (idx < N) ? cnt[idx] : 0;
        local[i] = s;          // exclusive prefix within thread
        s += v;
    }
    sh[t] = s;
    __syncthreads();
    for (int off = 1; off < 256; off <<= 1) {
        int v = (t >= off) ? sh[t - off] : 0;
        __syncthreads();
        sh[t] += v;            // inclusive scan of per-thread sums
        __syncthreads();
    }
    int tbase = bsum[blockIdx.x] + ((t > 0) ? sh[t - 1] : 0);
#pragma unroll
    for (int i = 0; i < 16; ++i) {
        int idx = base + i;
        if (idx < N) { int r = tbase + local[i]; rowptr[idx] = r; cursor[idx] = r; }
    }
    if (blockIdx.x == gridDim.x - 1 && t == 255) rowptr[N] = tbase + s;  // total = E
}

// ---------------- CSR fill + per-src norm-weight accumulation ----------------
__global__ __launch_bounds__(256) void fill_csr(const int* __restrict__ ei, int E,
                                                const float* __restrict__ dinv,
                                                int* __restrict__ cursor,
                                                int2* __restrict__ csr,
                                                float* __restrict__ srcw) {
    int e = blockIdx.x * 256 + threadIdx.x;
    if (e >= E) return;
    int src = ei[e];
    int dst = ei[E + e];
    float nrm = dinv[src] * dinv[dst];
    int pos = atomicAdd(&cursor[dst], 1);
    csr[pos] = make_int2(src, __float_as_int(nrm));
    unsafeAtomicAdd(&srcw[src], dinv[dst]);
}

// ---------------- GEMM: T[M x 128] = A[M x 128] @ W[128 x 128] ----------------
__global__ __launch_bounds__(256) void gemm128(const float* __restrict__ A,
                                               const float* __restrict__ W,
                                               float* __restrict__ T, int M) {
    __shared__ float Xs[64 * C];
    __shared__ float Wsh[64 * C];
    const int t = threadIdx.x;
    const int row0 = blockIdx.x * 64;

    const float4* A4 = (const float4*)A;
    float4* Xs4 = (float4*)Xs;
#pragma unroll
    for (int i = 0; i < 8; ++i) {
        int idx = t + i * 256;
        int r = idx >> 5;
        int gr = row0 + r;
        Xs4[idx] = (gr < M) ? A4[(size_t)gr * C4 + (idx & 31)]
                            : make_float4(0.f, 0.f, 0.f, 0.f);
    }

    const int cg = t & 31;
    const int rg = t >> 5;
    float4 acc[8];
#pragma unroll
    for (int i = 0; i < 8; ++i) acc[i] = make_float4(0.f, 0.f, 0.f, 0.f);

    const float4* W4 = (const float4*)W;
    float4* Ws4 = (float4*)Wsh;

    for (int kk = 0; kk < 2; ++kk) {
        __syncthreads();
#pragma unroll
        for (int i = 0; i < 8; ++i) {
            int idx = t + i * 256;
            Ws4[idx] = W4[kk * 2048 + idx];
        }
        __syncthreads();
#pragma unroll
        for (int k4 = 0; k4 < 16; ++k4) {
            float4 w0 = Ws4[(k4 * 4 + 0) * C4 + cg];
            float4 w1 = Ws4[(k4 * 4 + 1) * C4 + cg];
            float4 w2 = Ws4[(k4 * 4 + 2) * C4 + cg];
            float4 w3 = Ws4[(k4 * 4 + 3) * C4 + cg];
#pragma unroll
            for (int i = 0; i < 8; ++i) {
                float4 xv = Xs4[(rg * 8 + i) * C4 + kk * 16 + k4];
                acc[i].x = fmaf(xv.x, w0.x, fmaf(xv.y, w1.x, fmaf(xv.z, w2.x, fmaf(xv.w, w3.x, acc[i].x))));
                acc[i].y = fmaf(xv.x, w0.y, fmaf(xv.y, w1.y, fmaf(xv.z, w2.y, fmaf(xv.w, w3.y, acc[i].y))));
                acc[i].z = fmaf(xv.x, w0.z, fmaf(xv.y, w1.z, fmaf(xv.z, w2.z, fmaf(xv.w, w3.z, acc[i].z))));
                acc[i].w = fmaf(xv.x, w0.w, fmaf(xv.y, w1.w, fmaf(xv.z, w2.w, fmaf(xv.w, w3.w, acc[i].w))));
            }
        }
    }

    float4* T4 = (float4*)T;
#pragma unroll
    for (int i = 0; i < 8; ++i) {
        int gr = row0 + rg * 8 + i;
        if (gr < M) T4[(size_t)gr * C4 + cg] = acc[i];
    }
}

// ---------------- CSR aggregate, fused self-loop + bias + relu ----------------
// One wave per dst node; lane = 2 channels (float2).
__global__ __launch_bounds__(256) void agg_kernel(const int* __restrict__ rowptr,
                                                  const int2* __restrict__ csr,
                                                  const float* __restrict__ t,
                                                  const float* __restrict__ dinv,
                                                  const float* __restrict__ b,
                                                  float* __restrict__ h, int N) {
    int tid = blockIdx.x * 256 + threadIdx.x;
    int node = tid >> 6;
    if (node >= N) return;
    int lane = tid & 63;
    int beg = rowptr[node];
    int end = rowptr[node + 1];

    const float2* t2 = (const float2*)t;
    float2 acc = make_float2(0.f, 0.f);

    int k = beg;
    for (; k + 1 < end; k += 2) {
        int2 p0 = csr[k];
        int2 p1 = csr[k + 1];
        float2 v0 = t2[(size_t)p0.x * 64 + lane];
        float2 v1 = t2[(size_t)p1.x * 64 + lane];
        float n0 = __int_as_float(p0.y);
        float n1 = __int_as_float(p1.y);
        acc.x = fmaf(v0.x, n0, acc.x);
        acc.y = fmaf(v0.y, n0, acc.y);
        acc.x = fmaf(v1.x, n1, acc.x);
        acc.y = fmaf(v1.y, n1, acc.y);
    }
    if (k < end) {
        int2 p0 = csr[k];
        float2 v0 = t2[(size_t)p0.x * 64 + lane];
        float n0 = __int_as_float(p0.y);
        acc.x = fmaf(v0.x, n0, acc.x);
        acc.y = fmaf(v0.y, n0, acc.y);
    }

    float di = dinv[node];
    float s = di * di;
    float2 tv = t2[(size_t)node * 64 + lane];
    float2 bv = ((const float2*)b)[lane];
    acc.x = fmaxf(fmaf(tv.x, s, acc.x) + bv.x, 0.f);
    acc.y = fmaxf(fmaf(tv.y, s, acc.y) + bv.y, 0.f);
    ((float2*)h)[(size_t)node * 64 + lane] = acc;
}

// ---------------- weighted row-sum: v[c] = sum_i w_i * h[i][c] ----------------
__global__ __launch_bounds__(128) void wreduce(const float* __restrict__ h,
                                               const float* __restrict__ dinv,
                                               const float* __restrict__ srcw,
                                               float* __restrict__ v, int N, int npb) {
    int c = threadIdx.x;
    int i0 = blockIdx.x * npb;
    int i1 = min(i0 + npb, N);
    float s = 0.f;
    for (int i = i0; i < i1; ++i) {
        float di = dinv[i];
        float w = di * (di + srcw[i]);
        s = fmaf(h[(size_t)i * C + c], w, s);
    }
    unsafeAtomicAdd(&v[c], s);
}

// ---------------- out = (v @ W3)/N + b3 ----------------
__global__ __launch_bounds__(128) void matvec(const float* __restrict__ v,
                                              const float* __restrict__ W,
                                              const float* __restrict__ b,
                                              float* __restrict__ out, float invN) {
    int c = threadIdx.x;
    float s = 0.f;
    for (int k = 0; k < C; ++k) s = fmaf(v[k], W[(size_t)k * C + c], s);
    out[c] = s * invN + b[c];
}

extern "C" void kernel_launch(void* const* d_in, const int* in_sizes, int n_in,
                              void* d_out, int out_size, void* d_ws, size_t ws_size,
                              hipStream_t stream) {
    const float* x  = (const float*)d_in[0];
    const int*   ei = (const int*)d_in[1];
    const float* W1 = (const float*)d_in[2];
    const float* b1 = (const float*)d_in[3];
    const float* W2 = (const float*)d_in[4];
    const float* b2 = (const float*)d_in[5];
    const float* W3 = (const float*)d_in[6];
    const float* b3 = (const float*)d_in[7];
    float* out = (float*)d_out;

    const int N = in_sizes[0] / C;      // 50000
    const int E = in_sizes[1] / 2;      // 800000

    const size_t hbytes = (size_t)N * C * sizeof(float);   // 25.6 MB
    char* ws = (char*)d_ws;
    size_t off = 0;
    auto alloc = [&](size_t bytes) { char* p = ws + off; off += (bytes + 255) & ~(size_t)255; return p; };
    float* buf0   = (float*)alloc(hbytes);                    // t = h @ W
    float* buf1   = (float*)alloc(hbytes);                    // h
    int2*  csr    = (int2*)alloc((size_t)E * sizeof(int2));   // 6.4 MB
    int*   rowptr = (int*)alloc((size_t)(N + 1) * sizeof(int));
    int*   cursor = (int*)alloc((size_t)N * sizeof(int));
    int*   cnt    = (int*)alloc((size_t)N * sizeof(int));
    float* dinv   = (float*)alloc((size_t)N * sizeof(float));
    float* srcw   = (float*)alloc((size_t)N * sizeof(float));
    float* vsum   = (float*)alloc((size_t)C * sizeof(float));
    int*   bsum   = (int*)alloc(256 * sizeof(int));

    hipMemsetAsync(cnt, 0, (size_t)N * sizeof(int), stream);
    hipMemsetAsync(srcw, 0, (size_t)N * sizeof(float), stream);
    hipMemsetAsync(vsum, 0, (size_t)C * sizeof(float), stream);

    const int ebl = (E + 255) / 256;
    const int nb = (N + SCHUNK - 1) / SCHUNK;   // scan blocks (~13)
    deg_count<<<ebl, 256, 0, stream>>>(ei, E, cnt);
    dinv_kernel<<<(N + 255) / 256, 256, 0, stream>>>(cnt, dinv, N);
    scan_part<<<nb, 256, 0, stream>>>(cnt, bsum, N);
    scan_top<<<1, 64, 0, stream>>>(bsum, nb);
    scan_write<<<nb, 256, 0, stream>>>(cnt, bsum, rowptr, cursor, N);
    fill_csr<<<ebl, 256, 0, stream>>>(ei, E, dinv, cursor, csr, srcw);

    const int gb = (N + 63) / 64;
    const int ab = (int)(((long long)N * 64 + 255) / 256);
    const int rb = 391;
    const int npb = (N + rb - 1) / rb;

    // layer 1
    gemm128<<<gb, 256, 0, stream>>>(x, W1, buf0, N);
    agg_kernel<<<ab, 256, 0, stream>>>(rowptr, csr, buf0, dinv, b1, buf1, N);
    // layer 2
    gemm128<<<gb, 256, 0, stream>>>(buf1, W2, buf0, N);
    agg_kernel<<<ab, 256, 0, stream>>>(rowptr, csr, buf0, dinv, b2, buf1, N);
    // layer 3 collapsed: out = ((sum_i w_i h2[i]) @ W3)/N + b3
    wreduce<<<rb, 128, 0, stream>>>(buf1, dinv, srcw, vsum, N, npb);
    matvec<<<1, 128, 0, stream>>>(vsum, W3, b3, out, 1.0f / (float)N);
}

// Round 4
// 399.175 us; speedup vs baseline: 5.6103x; 1.0133x over previous
//
#include <hip/hip_runtime.h>
#include <hip/hip_bf16.h>

// GCN 3-layer embedder, CSR-gather formulation.
// Agg(t)[i] = dinv[i] * ( sum_{e: dst=i} dinv[src_e]*t[src_e] + dinv[i]*t[i] )
// CSR entries are ushort src ids (N=50000 < 65536); norms recomputed from dinv.
// Layer 3 + mean collapsed:
//   out = ((sum_i w_i * h2[i]) @ W3)/N + b3,  w_i = dinv_i^2 + dinv_i * sum_{e:src=i} dinv[dst_e]

#define C 128
#define C4 32
#define SCHUNK 4096   // nodes per scan block (256 threads x 16)

// ---------------- degree count (int atomics) ----------------
__global__ __launch_bounds__(256) void deg_count(const int* __restrict__ ei, int E,
                                                 int* __restrict__ cnt) {
    int i = blockIdx.x * 256 + threadIdx.x;
    if (i < E) atomicAdd(&cnt[ei[E + i]], 1);
}

// ---------------- scan stage 1: per-block sums (+ fused dinv) ----------------
__global__ __launch_bounds__(256) void scan_part(const int* __restrict__ cnt,
                                                 int* __restrict__ bsum,
                                                 float* __restrict__ dinv, int N) {
    __shared__ int sh[256];
    const int t = threadIdx.x;
    int base = blockIdx.x * SCHUNK + t * 16;
    int s = 0;
#pragma unroll
    for (int i = 0; i < 16; ++i) {
        int idx = base + i;
        if (idx < N) {
            int v = cnt[idx];
            s += v;
            dinv[idx] = rsqrtf((float)v + 1.0f);   // +1 = self loop
        }
    }
    sh[t] = s;
    __syncthreads();
    for (int off = 128; off > 0; off >>= 1) {
        if (t < off) sh[t] += sh[t + off];
        __syncthreads();
    }
    if (t == 0) bsum[blockIdx.x] = sh[0];
}

// ---------------- scan stage 2: write rowptr & cursor ----------------
__global__ __launch_bounds__(256) void scan_write(const int* __restrict__ cnt,
                                                  const int* __restrict__ bsum,
                                                  int* __restrict__ rowptr,
                                                  int* __restrict__ cursor, int N) {
    __shared__ int sh[256];
    const int t = threadIdx.x;
    int base = blockIdx.x * SCHUNK + t * 16;
    int local[16];
    int s = 0;
#pragma unroll
    for (int i = 0; i < 16; ++i) {
        int idx = base + i;
        int v = (idx < N) ? cnt[idx] : 0;
        local[i] = s;
        s += v;
    }
    sh[t] = s;
    __syncthreads();
    for (int off = 1; off < 256; off <<= 1) {
        int v = (t >= off) ? sh[t - off] : 0;
        __syncthreads();
        sh[t] += v;
        __syncthreads();
    }
    int blkbase = 0;
    for (int i = 0; i < (int)blockIdx.x; ++i) blkbase += bsum[i];   // nb <= 13
    int tbase = blkbase + ((t > 0) ? sh[t - 1] : 0);
#pragma unroll
    for (int i = 0; i < 16; ++i) {
        int idx = base + i;
        if (idx < N) { int r = tbase + local[i]; rowptr[idx] = r; cursor[idx] = r; }
    }
    if (blockIdx.x == gridDim.x - 1 && t == 255) rowptr[N] = tbase + s;  // = E
}

// ---------------- CSR fill (2B entries) + per-src norm-weight accumulation ----------------
__global__ __launch_bounds__(256) void fill_csr(const int* __restrict__ ei, int E,
                                                const float* __restrict__ dinv,
                                                int* __restrict__ cursor,
                                                ushort* __restrict__ csr,
                                                float* __restrict__ srcw) {
    int e = blockIdx.x * 256 + threadIdx.x;
    if (e >= E) return;
    int src = ei[e];
    int dst = ei[E + e];
    int pos = atomicAdd(&cursor[dst], 1);
    csr[pos] = (ushort)src;
    unsafeAtomicAdd(&srcw[src], dinv[dst]);
}

// ---------------- GEMM: T[M x 128] = A[M x 128] @ W[128 x 128] ----------------
__global__ __launch_bounds__(256) void gemm128(const float* __restrict__ A,
                                               const float* __restrict__ W,
                                               float* __restrict__ T, int M) {
    __shared__ float Xs[64 * C];
    __shared__ float Wsh[64 * C];
    const int t = threadIdx.x;
    const int row0 = blockIdx.x * 64;

    const float4* A4 = (const float4*)A;
    float4* Xs4 = (float4*)Xs;
#pragma unroll
    for (int i = 0; i < 8; ++i) {
        int idx = t + i * 256;
        int r = idx >> 5;
        int gr = row0 + r;
        Xs4[idx] = (gr < M) ? A4[(size_t)gr * C4 + (idx & 31)]
                            : make_float4(0.f, 0.f, 0.f, 0.f);
    }

    const int cg = t & 31;
    const int rg = t >> 5;
    float4 acc[8];
#pragma unroll
    for (int i = 0; i < 8; ++i) acc[i] = make_float4(0.f, 0.f, 0.f, 0.f);

    const float4* W4 = (const float4*)W;
    float4* Ws4 = (float4*)Wsh;

    for (int kk = 0; kk < 2; ++kk) {
        __syncthreads();
#pragma unroll
        for (int i = 0; i < 8; ++i) {
            int idx = t + i * 256;
            Ws4[idx] = W4[kk * 2048 + idx];
        }
        __syncthreads();
#pragma unroll
        for (int k4 = 0; k4 < 16; ++k4) {
            float4 w0 = Ws4[(k4 * 4 + 0) * C4 + cg];
            float4 w1 = Ws4[(k4 * 4 + 1) * C4 + cg];
            float4 w2 = Ws4[(k4 * 4 + 2) * C4 + cg];
            float4 w3 = Ws4[(k4 * 4 + 3) * C4 + cg];
#pragma unroll
            for (int i = 0; i < 8; ++i) {
                float4 xv = Xs4[(rg * 8 + i) * C4 + kk * 16 + k4];
                acc[i].x = fmaf(xv.x, w0.x, fmaf(xv.y, w1.x, fmaf(xv.z, w2.x, fmaf(xv.w, w3.x, acc[i].x))));
                acc[i].y = fmaf(xv.x, w0.y, fmaf(xv.y, w1.y, fmaf(xv.z, w2.y, fmaf(xv.w, w3.y, acc[i].y))));
                acc[i].z = fmaf(xv.x, w0.z, fmaf(xv.y, w1.z, fmaf(xv.z, w2.z, fmaf(xv.w, w3.z, acc[i].z))));
                acc[i].w = fmaf(xv.x, w0.w, fmaf(xv.y, w1.w, fmaf(xv.z, w2.w, fmaf(xv.w, w3.w, acc[i].w))));
            }
        }
    }

    float4* T4 = (float4*)T;
#pragma unroll
    for (int i = 0; i < 8; ++i) {
        int gr = row0 + rg * 8 + i;
        if (gr < M) T4[(size_t)gr * C4 + cg] = acc[i];
    }
}

// ---------------- CSR aggregate, fused self-loop + bias + relu ----------------
// One wave per dst node; lane = 2 channels. 16 lanes cooperatively stage 16 CSR
// entries + dinv[src], broadcast via shfl; unrolled-16 body keeps 16 row gathers in flight.
__global__ __launch_bounds__(256) void agg_kernel(const int* __restrict__ rowptr,
                                                  const ushort* __restrict__ csr,
                                                  const float* __restrict__ t,
                                                  const float* __restrict__ dinv,
                                                  const float* __restrict__ b,
                                                  float* __restrict__ h, int N) {
    int tid = blockIdx.x * 256 + threadIdx.x;
    int node = tid >> 6;
    if (node >= N) return;
    int lane = tid & 63;
    int beg = rowptr[node];
    int end = rowptr[node + 1];

    const float2* t2 = (const float2*)t;
    float di = dinv[node];
    float2 tv = t2[(size_t)node * 64 + lane];
    float2 acc = make_float2(di * tv.x, di * tv.y);   // self-loop (outer *di at end)

    for (int k0 = beg; k0 < end; k0 += 16) {
        int cn = end - k0; if (cn > 16) cn = 16;
        int s = 0; float w = 0.f;
        if (lane < 16 && lane < cn) { s = csr[k0 + lane]; w = dinv[s]; }
        if (cn == 16) {
#pragma unroll
            for (int j = 0; j < 16; ++j) {
                int sj = __shfl(s, j);
                float wj = __shfl(w, j);
                float2 v = t2[(size_t)sj * 64 + lane];
                acc.x = fmaf(v.x, wj, acc.x);
                acc.y = fmaf(v.y, wj, acc.y);
            }
        } else {
            for (int j = 0; j < cn; ++j) {
                int sj = __shfl(s, j);
                float wj = __shfl(w, j);
                float2 v = t2[(size_t)sj * 64 + lane];
                acc.x = fmaf(v.x, wj, acc.x);
                acc.y = fmaf(v.y, wj, acc.y);
            }
        }
    }

    float2 bv = ((const float2*)b)[lane];
    acc.x = fmaxf(fmaf(acc.x, di, bv.x), 0.f);
    acc.y = fmaxf(fmaf(acc.y, di, bv.y), 0.f);
    ((float2*)h)[(size_t)node * 64 + lane] = acc;
}

// ---------------- weighted row-sum: v[c] = sum_i w_i * h[i][c] ----------------
__global__ __launch_bounds__(128) void wreduce(const float* __restrict__ h,
                                               const float* __restrict__ dinv,
                                               const float* __restrict__ srcw,
                                               float* __restrict__ v, int N, int npb) {
    int c = threadIdx.x;
    int i0 = blockIdx.x * npb;
    int i1 = min(i0 + npb, N);
    float s = 0.f;
    for (int i = i0; i < i1; ++i) {
        float di = dinv[i];
        float w = di * (di + srcw[i]);
        s = fmaf(h[(size_t)i * C + c], w, s);
    }
    unsafeAtomicAdd(&v[c], s);
}

// ---------------- out = (v @ W3)/N + b3 ----------------
__global__ __launch_bounds__(128) void matvec(const float* __restrict__ v,
                                              const float* __restrict__ W,
                                              const float* __restrict__ b,
                                              float* __restrict__ out, float invN) {
    int c = threadIdx.x;
    float s = 0.f;
    for (int k = 0; k < C; ++k) s = fmaf(v[k], W[(size_t)k * C + c], s);
    out[c] = s * invN + b[c];
}

extern "C" void kernel_launch(void* const* d_in, const int* in_sizes, int n_in,
                              void* d_out, int out_size, void* d_ws, size_t ws_size,
                              hipStream_t stream) {
    const float* x  = (const float*)d_in[0];
    const int*   ei = (const int*)d_in[1];
    const float* W1 = (const float*)d_in[2];
    const float* b1 = (const float*)d_in[3];
    const float* W2 = (const float*)d_in[4];
    const float* b2 = (const float*)d_in[5];
    const float* W3 = (const float*)d_in[6];
    const float* b3 = (const float*)d_in[7];
    float* out = (float*)d_out;

    const int N = in_sizes[0] / C;      // 50000 (< 65536: ushort CSR entries)
    const int E = in_sizes[1] / 2;      // 800000

    const size_t hbytes = (size_t)N * C * sizeof(float);   // 25.6 MB
    char* ws = (char*)d_ws;
    size_t off = 0;
    auto alloc = [&](size_t bytes) { char* p = ws + off; off += (bytes + 255) & ~(size_t)255; return p; };
    float*  buf0   = (float*)alloc(hbytes);                      // t = h @ W
    float*  buf1   = (float*)alloc(hbytes);                      // h
    ushort* csr    = (ushort*)alloc((size_t)E * sizeof(ushort)); // 1.6 MB
    int*    rowptr = (int*)alloc((size_t)(N + 1) * sizeof(int));
    int*    cursor = (int*)alloc((size_t)N * sizeof(int));
    int*    cnt    = (int*)alloc((size_t)N * sizeof(int));
    float*  dinv   = (float*)alloc((size_t)N * sizeof(float));
    float*  srcw   = (float*)alloc((size_t)N * sizeof(float));
    float*  vsum   = (float*)alloc((size_t)C * sizeof(float));
    int*    bsum   = (int*)alloc(256 * sizeof(int));

    hipMemsetAsync(cnt, 0, (size_t)N * sizeof(int), stream);
    hipMemsetAsync(srcw, 0, (size_t)N * sizeof(float), stream);
    hipMemsetAsync(vsum, 0, (size_t)C * sizeof(float), stream);

    const int ebl = (E + 255) / 256;
    const int nb = (N + SCHUNK - 1) / SCHUNK;   // ~13
    deg_count<<<ebl, 256, 0, stream>>>(ei, E, cnt);
    scan_part<<<nb, 256, 0, stream>>>(cnt, bsum, dinv, N);
    scan_write<<<nb, 256, 0, stream>>>(cnt, bsum, rowptr, cursor, N);
    fill_csr<<<ebl, 256, 0, stream>>>(ei, E, dinv, cursor, csr, srcw);

    const int gb = (N + 63) / 64;
    const int ab = (int)(((long long)N * 64 + 255) / 256);
    const int rb = 391;
    const int npb = (N + rb - 1) / rb;

    // layer 1
    gemm128<<<gb, 256, 0, stream>>>(x, W1, buf0, N);
    agg_kernel<<<ab, 256, 0, stream>>>(rowptr, csr, buf0, dinv, b1, buf1, N);
    // layer 2
    gemm128<<<gb, 256, 0, stream>>>(buf1, W2, buf0, N);
    agg_kernel<<<ab, 256, 0, stream>>>(rowptr, csr, buf0, dinv, b2, buf1, N);
    // layer 3 collapsed: out = ((sum_i w_i h2[i]) @ W3)/N + b3
    wreduce<<<rb, 128, 0, stream>>>(buf1, dinv, srcw, vsum, N, npb);
    matvec<<<1, 128, 0, stream>>>(vsum, W3, b3, out, 1.0f / (float)N);
}

// Round 5
// 360.698 us; speedup vs baseline: 6.2088x; 1.1067x over previous
//
#include <hip/hip_runtime.h>
#include <hip/hip_bf16.h>
#include <hip/hip_fp16.h>

// GCN 3-layer embedder, CSR-gather formulation.
// Agg(t)[i] = dinv[i] * ( sum_{e: dst=i} dinv[src_e]*t[src_e] + dinv[i]*t[i] )
// t = h@W is stored fp16 (gather table); accumulation in f32.
// Layer 3 + mean collapsed:
//   out = ((sum_i w_i * h2[i]) @ W3)/N + b3,  w_i = dinv_i^2 + dinv_i * sum_{e:src=i} dinv[dst_e]

#define C 128
#define C4 32
#define SCHUNK 4096   // nodes per scan block (256 threads x 16)

// ---------------- degree count (int atomics), 4 edges/thread ----------------
__global__ __launch_bounds__(256) void deg_count(const int* __restrict__ ei, int E,
                                                 int* __restrict__ cnt) {
    int base = (blockIdx.x * 256 + threadIdx.x) * 4;
#pragma unroll
    for (int j = 0; j < 4; ++j) {
        int i = base + j;
        if (i < E) atomicAdd(&cnt[ei[E + i]], 1);
    }
}

// ---------------- scan stage 1: per-block sums (+ fused dinv) ----------------
__global__ __launch_bounds__(256) void scan_part(const int* __restrict__ cnt,
                                                 int* __restrict__ bsum,
                                                 float* __restrict__ dinv, int N) {
    __shared__ int sh[256];
    const int t = threadIdx.x;
    int base = blockIdx.x * SCHUNK + t * 16;
    int s = 0;
#pragma unroll
    for (int i = 0; i < 16; ++i) {
        int idx = base + i;
        if (idx < N) {
            int v = cnt[idx];
            s += v;
            dinv[idx] = rsqrtf((float)v + 1.0f);   // +1 = self loop
        }
    }
    sh[t] = s;
    __syncthreads();
    for (int off = 128; off > 0; off >>= 1) {
        if (t < off) sh[t] += sh[t + off];
        __syncthreads();
    }
    if (t == 0) bsum[blockIdx.x] = sh[0];
}

// ---------------- scan stage 2: write rowptr & cursor ----------------
__global__ __launch_bounds__(256) void scan_write(const int* __restrict__ cnt,
                                                  const int* __restrict__ bsum,
                                                  int* __restrict__ rowptr,
                                                  int* __restrict__ cursor, int N) {
    __shared__ int sh[256];
    const int t = threadIdx.x;
    int base = blockIdx.x * SCHUNK + t * 16;
    int local[16];
    int s = 0;
#pragma unroll
    for (int i = 0; i < 16; ++i) {
        int idx = base + i;
        int v = (idx < N) ? cnt[idx] : 0;
        local[i] = s;
        s += v;
    }
    sh[t] = s;
    __syncthreads();
    for (int off = 1; off < 256; off <<= 1) {
        int v = (t >= off) ? sh[t - off] : 0;
        __syncthreads();
        sh[t] += v;
        __syncthreads();
    }
    int blkbase = 0;
    for (int i = 0; i < (int)blockIdx.x; ++i) blkbase += bsum[i];   // nb <= 13
    int tbase = blkbase + ((t > 0) ? sh[t - 1] : 0);
#pragma unroll
    for (int i = 0; i < 16; ++i) {
        int idx = base + i;
        if (idx < N) { int r = tbase + local[i]; rowptr[idx] = r; cursor[idx] = r; }
    }
    if (blockIdx.x == gridDim.x - 1 && t == 255) rowptr[N] = tbase + s;  // = E
}

// ---------------- CSR fill (2B entries) + srcw accumulation, 4 edges/thread ----------------
__global__ __launch_bounds__(256) void fill_csr(const int* __restrict__ ei, int E,
                                                const float* __restrict__ dinv,
                                                int* __restrict__ cursor,
                                                ushort* __restrict__ csr,
                                                float* __restrict__ srcw) {
    int base = (blockIdx.x * 256 + threadIdx.x) * 4;
    int src[4], dst[4];
    bool ok[4];
#pragma unroll
    for (int j = 0; j < 4; ++j) {
        int e = base + j;
        ok[j] = e < E;
        if (ok[j]) { src[j] = ei[e]; dst[j] = ei[E + e]; }
    }
    int pos[4];
#pragma unroll
    for (int j = 0; j < 4; ++j)
        if (ok[j]) pos[j] = atomicAdd(&cursor[dst[j]], 1);    // 4 independent atomic chains
#pragma unroll
    for (int j = 0; j < 4; ++j)
        if (ok[j]) csr[pos[j]] = (ushort)src[j];
#pragma unroll
    for (int j = 0; j < 4; ++j)
        if (ok[j]) unsafeAtomicAdd(&srcw[src[j]], dinv[dst[j]]);
}

// ---------------- GEMM: T[M x 128] = A[M x 128] @ W[128 x 128], fp16 output ----------------
__global__ __launch_bounds__(256) void gemm128(const float* __restrict__ A,
                                               const float* __restrict__ W,
                                               ushort* __restrict__ T, int M) {
    __shared__ float Xs[64 * C];
    __shared__ float Wsh[64 * C];
    const int t = threadIdx.x;
    const int row0 = blockIdx.x * 64;

    const float4* A4 = (const float4*)A;
    float4* Xs4 = (float4*)Xs;
#pragma unroll
    for (int i = 0; i < 8; ++i) {
        int idx = t + i * 256;
        int r = idx >> 5;
        int gr = row0 + r;
        Xs4[idx] = (gr < M) ? A4[(size_t)gr * C4 + (idx & 31)]
                            : make_float4(0.f, 0.f, 0.f, 0.f);
    }

    const int cg = t & 31;
    const int rg = t >> 5;
    float4 acc[8];
#pragma unroll
    for (int i = 0; i < 8; ++i) acc[i] = make_float4(0.f, 0.f, 0.f, 0.f);

    const float4* W4 = (const float4*)W;
    float4* Ws4 = (float4*)Wsh;

    for (int kk = 0; kk < 2; ++kk) {
        __syncthreads();
#pragma unroll
        for (int i = 0; i < 8; ++i) {
            int idx = t + i * 256;
            Ws4[idx] = W4[kk * 2048 + idx];
        }
        __syncthreads();
#pragma unroll
        for (int k4 = 0; k4 < 16; ++k4) {
            float4 w0 = Ws4[(k4 * 4 + 0) * C4 + cg];
            float4 w1 = Ws4[(k4 * 4 + 1) * C4 + cg];
            float4 w2 = Ws4[(k4 * 4 + 2) * C4 + cg];
            float4 w3 = Ws4[(k4 * 4 + 3) * C4 + cg];
#pragma unroll
            for (int i = 0; i < 8; ++i) {
                float4 xv = Xs4[(rg * 8 + i) * C4 + kk * 16 + k4];
                acc[i].x = fmaf(xv.x, w0.x, fmaf(xv.y, w1.x, fmaf(xv.z, w2.x, fmaf(xv.w, w3.x, acc[i].x))));
                acc[i].y = fmaf(xv.x, w0.y, fmaf(xv.y, w1.y, fmaf(xv.z, w2.y, fmaf(xv.w, w3.y, acc[i].y))));
                acc[i].z = fmaf(xv.x, w0.z, fmaf(xv.y, w1.z, fmaf(xv.z, w2.z, fmaf(xv.w, w3.z, acc[i].z))));
                acc[i].w = fmaf(xv.x, w0.w, fmaf(xv.y, w1.w, fmaf(xv.z, w2.w, fmaf(xv.w, w3.w, acc[i].w))));
            }
        }
    }

    uint2* T2 = (uint2*)T;
#pragma unroll
    for (int i = 0; i < 8; ++i) {
        int gr = row0 + rg * 8 + i;
        if (gr < M) {
            __half2 p0 = __floats2half2_rn(acc[i].x, acc[i].y);
            __half2 p1 = __floats2half2_rn(acc[i].z, acc[i].w);
            uint2 u;
            u.x = *(const unsigned int*)&p0;
            u.y = *(const unsigned int*)&p1;
            T2[(size_t)gr * 32 + cg] = u;   // row stride: 128 half = 32 uint2
        }
    }
}

// ---------------- CSR aggregate (fp16 gather, f32 accum), fused self-loop+bias+relu ----------------
// One wave per dst node; lane = 2 channels (__half2). 16 lanes stage 16 CSR entries
// + dinv[src], broadcast via shfl; unrolled-16 body keeps 16 row gathers in flight.
__global__ __launch_bounds__(256) void agg_kernel(const int* __restrict__ rowptr,
                                                  const ushort* __restrict__ csr,
                                                  const __half2* __restrict__ t2,
                                                  const float* __restrict__ dinv,
                                                  const float* __restrict__ b,
                                                  float* __restrict__ h, int N) {
    int tid = blockIdx.x * 256 + threadIdx.x;
    int node = tid >> 6;
    if (node >= N) return;
    int lane = tid & 63;
    int beg = rowptr[node];
    int end = rowptr[node + 1];

    float di = dinv[node];
    float2 tv = __half22float2(t2[(size_t)node * 64 + lane]);
    float2 acc = make_float2(di * tv.x, di * tv.y);   // self-loop (outer *di at end)

    for (int k0 = beg; k0 < end; k0 += 16) {
        int cn = end - k0; if (cn > 16) cn = 16;
        int s = 0; float w = 0.f;
        if (lane < 16 && lane < cn) { s = csr[k0 + lane]; w = dinv[s]; }
        if (cn == 16) {
#pragma unroll
            for (int j = 0; j < 16; ++j) {
                int sj = __shfl(s, j);
                float wj = __shfl(w, j);
                float2 v = __half22float2(t2[(size_t)sj * 64 + lane]);
                acc.x = fmaf(v.x, wj, acc.x);
                acc.y = fmaf(v.y, wj, acc.y);
            }
        } else {
            for (int j = 0; j < cn; ++j) {
                int sj = __shfl(s, j);
                float wj = __shfl(w, j);
                float2 v = __half22float2(t2[(size_t)sj * 64 + lane]);
                acc.x = fmaf(v.x, wj, acc.x);
                acc.y = fmaf(v.y, wj, acc.y);
            }
        }
    }

    float2 bv = ((const float2*)b)[lane];
    acc.x = fmaxf(fmaf(acc.x, di, bv.x), 0.f);
    acc.y = fmaxf(fmaf(acc.y, di, bv.y), 0.f);
    ((float2*)h)[(size_t)node * 64 + lane] = acc;
}

// ---------------- weighted row-sum: v[c] = sum_i w_i * h[i][c] ----------------
__global__ __launch_bounds__(128) void wreduce(const float* __restrict__ h,
                                               const float* __restrict__ dinv,
                                               const float* __restrict__ srcw,
                                               float* __restrict__ v, int N, int npb) {
    int c = threadIdx.x;
    int i0 = blockIdx.x * npb;
    int i1 = min(i0 + npb, N);
    float s = 0.f;
    for (int i = i0; i < i1; ++i) {
        float di = dinv[i];
        float w = di * (di + srcw[i]);
        s = fmaf(h[(size_t)i * C + c], w, s);
    }
    unsafeAtomicAdd(&v[c], s);
}

// ---------------- out = (v @ W3)/N + b3 ----------------
__global__ __launch_bounds__(128) void matvec(const float* __restrict__ v,
                                              const float* __restrict__ W,
                                              const float* __restrict__ b,
                                              float* __restrict__ out, float invN) {
    int c = threadIdx.x;
    float s = 0.f;
    for (int k = 0; k < C; ++k) s = fmaf(v[k], W[(size_t)k * C + c], s);
    out[c] = s * invN + b[c];
}

extern "C" void kernel_launch(void* const* d_in, const int* in_sizes, int n_in,
                              void* d_out, int out_size, void* d_ws, size_t ws_size,
                              hipStream_t stream) {
    const float* x  = (const float*)d_in[0];
    const int*   ei = (const int*)d_in[1];
    const float* W1 = (const float*)d_in[2];
    const float* b1 = (const float*)d_in[3];
    const float* W2 = (const float*)d_in[4];
    const float* b2 = (const float*)d_in[5];
    const float* W3 = (const float*)d_in[6];
    const float* b3 = (const float*)d_in[7];
    float* out = (float*)d_out;

    const int N = in_sizes[0] / C;      // 50000 (< 65536: ushort CSR entries)
    const int E = in_sizes[1] / 2;      // 800000

    const size_t hbytes = (size_t)N * C * sizeof(float);   // 25.6 MB
    char* ws = (char*)d_ws;
    size_t off = 0;
    auto alloc = [&](size_t bytes) { char* p = ws + off; off += (bytes + 255) & ~(size_t)255; return p; };
    ushort* tbuf   = (ushort*)alloc((size_t)N * C * sizeof(ushort)); // t = h @ W (fp16)
    float*  buf1   = (float*)alloc(hbytes);                          // h (f32)
    ushort* csr    = (ushort*)alloc((size_t)E * sizeof(ushort));     // 1.6 MB
    int*    rowptr = (int*)alloc((size_t)(N + 1) * sizeof(int));
    int*    cursor = (int*)alloc((size_t)N * sizeof(int));
    int*    cnt    = (int*)alloc((size_t)N * sizeof(int));
    float*  dinv   = (float*)alloc((size_t)N * sizeof(float));
    float*  srcw   = (float*)alloc((size_t)N * sizeof(float));
    float*  vsum   = (float*)alloc((size_t)C * sizeof(float));
    int*    bsum   = (int*)alloc(256 * sizeof(int));

    hipMemsetAsync(cnt, 0, (size_t)N * sizeof(int), stream);
    hipMemsetAsync(srcw, 0, (size_t)N * sizeof(float), stream);
    hipMemsetAsync(vsum, 0, (size_t)C * sizeof(float), stream);

    const int ebl4 = (E + 1023) / 1024;         // 4 edges per thread
    const int nb = (N + SCHUNK - 1) / SCHUNK;   // ~13
    deg_count<<<ebl4, 256, 0, stream>>>(ei, E, cnt);
    scan_part<<<nb, 256, 0, stream>>>(cnt, bsum, dinv, N);
    scan_write<<<nb, 256, 0, stream>>>(cnt, bsum, rowptr, cursor, N);
    fill_csr<<<ebl4, 256, 0, stream>>>(ei, E, dinv, cursor, csr, srcw);

    const int gb = (N + 63) / 64;
    const int ab = (int)(((long long)N * 64 + 255) / 256);
    const int rb = 391;
    const int npb = (N + rb - 1) / rb;

    // layer 1
    gemm128<<<gb, 256, 0, stream>>>(x, W1, tbuf, N);
    agg_kernel<<<ab, 256, 0, stream>>>(rowptr, csr, (const __half2*)tbuf, dinv, b1, buf1, N);
    // layer 2
    gemm128<<<gb, 256, 0, stream>>>(buf1, W2, tbuf, N);
    agg_kernel<<<ab, 256, 0, stream>>>(rowptr, csr, (const __half2*)tbuf, dinv, b2, buf1, N);
    // layer 3 collapsed: out = ((sum_i w_i h2[i]) @ W3)/N + b3
    wreduce<<<rb, 128, 0, stream>>>(buf1, dinv, srcw, vsum, N, npb);
    matvec<<<1, 128, 0, stream>>>(vsum, W3, b3, out, 1.0f / (float)N);
}

// Round 6
// 297.965 us; speedup vs baseline: 7.5160x; 1.2105x over previous
//
#include <hip/hip_runtime.h>
#include <hip/hip_bf16.h>
#include <hip/hip_fp16.h>

// GCN 3-layer embedder, CSR-gather + fp16 MFMA GEMM.
// Agg(t)[i] = dinv[i] * ( sum_{e: dst=i} dinv[src_e]*t[src_e] + dinv[i]*t[i] )
// t = h@W via v_mfma_f32_16x16x32_f16 (fp16 in, f32 acc), stored fp16.
// Layer 3 + mean collapsed:
//   out = ((sum_i w_i * h2[i]) @ W3)/N + b3,  w_i = dinv_i^2 + dinv_i * sum_{e:src=i} dinv[dst_e]

#define C 128
#define C4 32
#define SCHUNK 4096

typedef __attribute__((ext_vector_type(8))) _Float16 half8;
typedef __attribute__((ext_vector_type(4))) float float4v;

// ---------------- degree count (int atomics), 4 edges/thread ----------------
__global__ __launch_bounds__(256) void deg_count(const int* __restrict__ ei, int E,
                                                 int* __restrict__ cnt) {
    int base = (blockIdx.x * 256 + threadIdx.x) * 4;
#pragma unroll
    for (int j = 0; j < 4; ++j) {
        int i = base + j;
        if (i < E) atomicAdd(&cnt[ei[E + i]], 1);
    }
}

// ---------------- scan stage 1: per-block sums (+ fused dinv) ----------------
__global__ __launch_bounds__(256) void scan_part(const int* __restrict__ cnt,
                                                 int* __restrict__ bsum,
                                                 float* __restrict__ dinv, int N) {
    __shared__ int sh[256];
    const int t = threadIdx.x;
    int base = blockIdx.x * SCHUNK + t * 16;
    int s = 0;
#pragma unroll
    for (int i = 0; i < 16; ++i) {
        int idx = base + i;
        if (idx < N) {
            int v = cnt[idx];
            s += v;
            dinv[idx] = rsqrtf((float)v + 1.0f);
        }
    }
    sh[t] = s;
    __syncthreads();
    for (int off = 128; off > 0; off >>= 1) {
        if (t < off) sh[t] += sh[t + off];
        __syncthreads();
    }
    if (t == 0) bsum[blockIdx.x] = sh[0];
}

// ---------------- scan stage 2: write rowptr & cursor ----------------
__global__ __launch_bounds__(256) void scan_write(const int* __restrict__ cnt,
                                                  const int* __restrict__ bsum,
                                                  int* __restrict__ rowptr,
                                                  int* __restrict__ cursor, int N) {
    __shared__ int sh[256];
    const int t = threadIdx.x;
    int base = blockIdx.x * SCHUNK + t * 16;
    int local[16];
    int s = 0;
#pragma unroll
    for (int i = 0; i < 16; ++i) {
        int idx = base + i;
        int v = (idx < N) ? cnt[idx] : 0;
        local[i] = s;
        s += v;
    }
    sh[t] = s;
    __syncthreads();
    for (int off = 1; off < 256; off <<= 1) {
        int v = (t >= off) ? sh[t - off] : 0;
        __syncthreads();
        sh[t] += v;
        __syncthreads();
    }
    int blkbase = 0;
    for (int i = 0; i < (int)blockIdx.x; ++i) blkbase += bsum[i];
    int tbase = blkbase + ((t > 0) ? sh[t - 1] : 0);
#pragma unroll
    for (int i = 0; i < 16; ++i) {
        int idx = base + i;
        if (idx < N) { int r = tbase + local[i]; rowptr[idx] = r; cursor[idx] = r; }
    }
    if (blockIdx.x == gridDim.x - 1 && t == 255) rowptr[N] = tbase + s;
}

// ---------------- CSR fill (2B entries) + srcw accumulation, 4 edges/thread ----------------
__global__ __launch_bounds__(256) void fill_csr(const int* __restrict__ ei, int E,
                                                const float* __restrict__ dinv,
                                                int* __restrict__ cursor,
                                                ushort* __restrict__ csr,
                                                float* __restrict__ srcw) {
    int base = (blockIdx.x * 256 + threadIdx.x) * 4;
    int src[4], dst[4];
    bool ok[4];
#pragma unroll
    for (int j = 0; j < 4; ++j) {
        int e = base + j;
        ok[j] = e < E;
        if (ok[j]) { src[j] = ei[e]; dst[j] = ei[E + e]; }
    }
    int pos[4];
#pragma unroll
    for (int j = 0; j < 4; ++j)
        if (ok[j]) pos[j] = atomicAdd(&cursor[dst[j]], 1);
#pragma unroll
    for (int j = 0; j < 4; ++j)
        if (ok[j]) csr[pos[j]] = (ushort)src[j];
#pragma unroll
    for (int j = 0; j < 4; ++j)
        if (ok[j]) unsafeAtomicAdd(&srcw[src[j]], dinv[dst[j]]);
}

// ---------------- weight prep: Wt[c][k] = (fp16) W[k][c], for W1,W2 ----------------
__global__ __launch_bounds__(128) void wprep(const float* __restrict__ W1,
                                             const float* __restrict__ W2,
                                             __half* __restrict__ Wt1,
                                             __half* __restrict__ Wt2) {
    const float* W = blockIdx.y ? W2 : W1;
    __half* Wt = blockIdx.y ? Wt2 : Wt1;
    int c = blockIdx.x, k = threadIdx.x;
    Wt[c * 128 + k] = __float2half(W[k * 128 + c]);
}

// ---------------- MFMA GEMM: T[M x 128] = A[M x 128] @ W, fp16 out ----------------
// Wt: fp16 [col][k] (transposed). Block = 64 rows; wave w = rows w*16..w*16+15.
// v_mfma_f32_16x16x32_f16: A lane(row=l&15, k=(l>>4)*8+j); B lane(col=l&15, same k);
// C/D lane(col=l&15, row=(l>>4)*4+reg)  [verified m89/m91].
template<bool AF32>
__global__ __launch_bounds__(256) void gemm_mfma(const void* __restrict__ Aptr,
                                                 const __half* __restrict__ Wt,
                                                 ushort* __restrict__ T, int M) {
    __shared__ _Float16 Wsh[128 * 128];   // 32 KB, XOR-swizzled rows (row = col of W)
    const int t = threadIdx.x;

    // stage Wt with swizzle: float4 idx; row = idx>>4 (16 float4 per 128-half row)
    const float4* Wg4 = (const float4*)Wt;
    float4* Ws4 = (float4*)Wsh;
#pragma unroll
    for (int i = 0; i < 8; ++i) {
        int idx = t + i * 256;
        int row = idx >> 4;
        Ws4[(idx & ~15) | ((idx ^ row) & 7) | (idx & 8)] = Wg4[idx];
    }
    // NOTE: swizzle must only XOR bits 0..2 of the within-row float4 index with row&7:
    // within-row f4 index = idx&15 (0..15); swizzled = (idx&15) ^ (row&7) applied to low 3 bits.

    const int wave = t >> 6, lane = t & 63;
    const int row0 = blockIdx.x * 64 + wave * 16;
    const int lr = lane & 15;        // A row / B,C col (within tile)
    const int lk = lane >> 4;        // k-group (A/B) / row-group (C)

    // A fragments: 4 k-steps x 8 halves
    half8 afrag[4];
    {
        int gr = row0 + lr; if (gr >= M) gr = M - 1;
        if (AF32) {
            const float* A = (const float*)Aptr;
            const float* ap = A + (size_t)gr * 128 + lk * 8;
#pragma unroll
            for (int ks = 0; ks < 4; ++ks) {
                float4 v0 = *(const float4*)(ap + ks * 32);
                float4 v1 = *(const float4*)(ap + ks * 32 + 4);
                half8 a;
                a[0] = (_Float16)v0.x; a[1] = (_Float16)v0.y; a[2] = (_Float16)v0.z; a[3] = (_Float16)v0.w;
                a[4] = (_Float16)v1.x; a[5] = (_Float16)v1.y; a[6] = (_Float16)v1.z; a[7] = (_Float16)v1.w;
                afrag[ks] = a;
            }
        } else {
            const _Float16* A = (const _Float16*)Aptr;
            const _Float16* ap = A + (size_t)gr * 128 + lk * 8;
#pragma unroll
            for (int ks = 0; ks < 4; ++ks) afrag[ks] = *(const half8*)(ap + ks * 32);
        }
    }

    __syncthreads();

    float4v acc[8];
#pragma unroll
    for (int n = 0; n < 8; ++n) acc[n] = (float4v)0.f;

#pragma unroll
    for (int n = 0; n < 8; ++n) {
        int brow = n * 16 + lr;                   // Wt row (= output col)
#pragma unroll
        for (int ks = 0; ks < 4; ++ks) {
            int f4 = ks * 4 + lk;                 // within-row float4 index (0..15)
            int swz = (f4 & 8) | ((f4 ^ brow) & 7);
            half8 b = *(const half8*)(Wsh + (size_t)brow * 128 + swz * 8);
            acc[n] = __builtin_amdgcn_mfma_f32_16x16x32_f16(afrag[ks], b, acc[n], 0, 0, 0);
        }
    }

#pragma unroll
    for (int n = 0; n < 8; ++n) {
#pragma unroll
        for (int r = 0; r < 4; ++r) {
            int gr = row0 + lk * 4 + r;
            if (gr < M) {
                __half hv = __float2half(acc[n][r]);
                T[(size_t)gr * 128 + n * 16 + lr] = *(const ushort*)&hv;
            }
        }
    }
}

// ---------------- CSR aggregate (fp16 gather, f32 accum), fp16 out ----------------
__global__ __launch_bounds__(256) void agg_kernel(const int* __restrict__ rowptr,
                                                  const ushort* __restrict__ csr,
                                                  const __half2* __restrict__ t2,
                                                  const float* __restrict__ dinv,
                                                  const float* __restrict__ b,
                                                  __half2* __restrict__ h, int N) {
    int tid = blockIdx.x * 256 + threadIdx.x;
    int node = tid >> 6;
    if (node >= N) return;
    int lane = tid & 63;
    int beg = rowptr[node];
    int end = rowptr[node + 1];

    float di = dinv[node];
    float2 tv = __half22float2(t2[(size_t)node * 64 + lane]);
    float2 acc = make_float2(di * tv.x, di * tv.y);

    for (int k0 = beg; k0 < end; k0 += 16) {
        int cn = end - k0; if (cn > 16) cn = 16;
        int s = 0; float w = 0.f;
        if (lane < 16 && lane < cn) { s = csr[k0 + lane]; w = dinv[s]; }
        if (cn == 16) {
#pragma unroll
            for (int j = 0; j < 16; ++j) {
                int sj = __shfl(s, j);
                float wj = __shfl(w, j);
                float2 v = __half22float2(t2[(size_t)sj * 64 + lane]);
                acc.x = fmaf(v.x, wj, acc.x);
                acc.y = fmaf(v.y, wj, acc.y);
            }
        } else {
            for (int j = 0; j < cn; ++j) {
                int sj = __shfl(s, j);
                float wj = __shfl(w, j);
                float2 v = __half22float2(t2[(size_t)sj * 64 + lane]);
                acc.x = fmaf(v.x, wj, acc.x);
                acc.y = fmaf(v.y, wj, acc.y);
            }
        }
    }

    float2 bv = ((const float2*)b)[lane];
    acc.x = fmaxf(fmaf(acc.x, di, bv.x), 0.f);
    acc.y = fmaxf(fmaf(acc.y, di, bv.y), 0.f);
    h[(size_t)node * 64 + lane] = __floats2half2_rn(acc.x, acc.y);
}

// ---------------- weighted row-sum over fp16 h: v[c] = sum_i w_i * h[i][c] ----------------
__global__ __launch_bounds__(128) void wreduce(const __half* __restrict__ h,
                                               const float* __restrict__ dinv,
                                               const float* __restrict__ srcw,
                                               float* __restrict__ v, int N, int npb) {
    int c = threadIdx.x;
    int i0 = blockIdx.x * npb;
    int i1 = min(i0 + npb, N);
    float s = 0.f;
    for (int i = i0; i < i1; ++i) {
        float di = dinv[i];
        float w = di * (di + srcw[i]);
        s = fmaf(__half2float(h[(size_t)i * C + c]), w, s);
    }
    unsafeAtomicAdd(&v[c], s);
}

// ---------------- out = (v @ W3)/N + b3 ----------------
__global__ __launch_bounds__(128) void matvec(const float* __restrict__ v,
                                              const float* __restrict__ W,
                                              const float* __restrict__ b,
                                              float* __restrict__ out, float invN) {
    int c = threadIdx.x;
    float s = 0.f;
    for (int k = 0; k < C; ++k) s = fmaf(v[k], W[(size_t)k * C + c], s);
    out[c] = s * invN + b[c];
}

extern "C" void kernel_launch(void* const* d_in, const int* in_sizes, int n_in,
                              void* d_out, int out_size, void* d_ws, size_t ws_size,
                              hipStream_t stream) {
    const float* x  = (const float*)d_in[0];
    const int*   ei = (const int*)d_in[1];
    const float* W1 = (const float*)d_in[2];
    const float* b1 = (const float*)d_in[3];
    const float* W2 = (const float*)d_in[4];
    const float* b2 = (const float*)d_in[5];
    const float* W3 = (const float*)d_in[6];
    const float* b3 = (const float*)d_in[7];
    float* out = (float*)d_out;

    const int N = in_sizes[0] / C;      // 50000
    const int E = in_sizes[1] / 2;      // 800000

    char* ws = (char*)d_ws;
    size_t off = 0;
    auto alloc = [&](size_t bytes) { char* p = ws + off; off += (bytes + 255) & ~(size_t)255; return p; };
    ushort* tbuf   = (ushort*)alloc((size_t)N * C * sizeof(ushort)); // t (fp16)
    ushort* hbuf   = (ushort*)alloc((size_t)N * C * sizeof(ushort)); // h (fp16)
    ushort* csr    = (ushort*)alloc((size_t)E * sizeof(ushort));
    int*    rowptr = (int*)alloc((size_t)(N + 1) * sizeof(int));
    int*    cursor = (int*)alloc((size_t)N * sizeof(int));
    int*    cnt    = (int*)alloc((size_t)N * sizeof(int));
    float*  dinv   = (float*)alloc((size_t)N * sizeof(float));
    float*  srcw   = (float*)alloc((size_t)N * sizeof(float));
    float*  vsum   = (float*)alloc((size_t)C * sizeof(float));
    int*    bsum   = (int*)alloc(256 * sizeof(int));
    __half* Wt1    = (__half*)alloc((size_t)C * C * sizeof(__half));
    __half* Wt2    = (__half*)alloc((size_t)C * C * sizeof(__half));

    hipMemsetAsync(cnt, 0, (size_t)N * sizeof(int), stream);
    hipMemsetAsync(srcw, 0, (size_t)N * sizeof(float), stream);
    hipMemsetAsync(vsum, 0, (size_t)C * sizeof(float), stream);

    const int ebl4 = (E + 1023) / 1024;
    const int nb = (N + SCHUNK - 1) / SCHUNK;
    deg_count<<<ebl4, 256, 0, stream>>>(ei, E, cnt);
    scan_part<<<nb, 256, 0, stream>>>(cnt, bsum, dinv, N);
    scan_write<<<nb, 256, 0, stream>>>(cnt, bsum, rowptr, cursor, N);
    fill_csr<<<ebl4, 256, 0, stream>>>(ei, E, dinv, cursor, csr, srcw);
    wprep<<<dim3(128, 2), 128, 0, stream>>>(W1, W2, Wt1, Wt2);

    const int gb = (N + 63) / 64;
    const int ab = (int)(((long long)N * 64 + 255) / 256);
    const int rb = 391;
    const int npb = (N + rb - 1) / rb;

    // layer 1
    gemm_mfma<true><<<gb, 256, 0, stream>>>(x, Wt1, tbuf, N);
    agg_kernel<<<ab, 256, 0, stream>>>(rowptr, csr, (const __half2*)tbuf, dinv, b1, (__half2*)hbuf, N);
    // layer 2
    gemm_mfma<false><<<gb, 256, 0, stream>>>(hbuf, Wt2, tbuf, N);
    agg_kernel<<<ab, 256, 0, stream>>>(rowptr, csr, (const __half2*)tbuf, dinv, b2, (__half2*)hbuf, N);
    // layer 3 collapsed
    wreduce<<<rb, 128, 0, stream>>>((const __half*)hbuf, dinv, srcw, vsum, N, npb);
    matvec<<<1, 128, 0, stream>>>(vsum, W3, b3, out, 1.0f / (float)N);
}

// Round 7
// 239.604 us; speedup vs baseline: 9.3467x; 1.2436x over previous
//
#include <hip/hip_runtime.h>
#include <hip/hip_bf16.h>
#include <hip/hip_fp16.h>

// GCN 3-layer embedder. CSR built via two-level counting sort (no per-edge
// global atomic-with-return). GEMMs via v_mfma_f32_16x16x32_f16, tables fp16.
// Agg(t)[i] = dinv[i] * ( sum_{e: dst=i} dinv[src_e]*t[src_e] + dinv[i]*t[i] )
// Layer 3 + mean collapsed:
//   out = ((sum_i w_i * h2[i]) @ W3)/N + b3,  w_i = dinv_i^2 + dinv_i * sum_{e:src=i} dinv[dst_e]

#define C 128
#define EPB 4096   // edges per block in binning kernels (256 thr x 16)

typedef __attribute__((ext_vector_type(8))) _Float16 half8;
typedef __attribute__((ext_vector_type(4))) float float4v;

// ---------------- B1: coarse histogram of dst>>8 ----------------
__global__ __launch_bounds__(256) void coarse_hist(const int* __restrict__ ei, int E,
                                                   int* __restrict__ ccnt) {
    __shared__ int hist[256];
    const int t = threadIdx.x;
    hist[t] = 0;
    __syncthreads();
    int base = blockIdx.x * EPB;
#pragma unroll
    for (int i = 0; i < 16; ++i) {
        int e = base + t + i * 256;
        if (e < E) atomicAdd(&hist[ei[E + e] >> 8], 1);
    }
    __syncthreads();
    if (hist[t]) atomicAdd(&ccnt[t], hist[t]);
}

// ---------------- B2: exclusive scan of coarse counts ----------------
__global__ __launch_bounds__(256) void scan_coarse(const int* __restrict__ ccnt,
                                                   int* __restrict__ cbase,
                                                   int* __restrict__ ccur,
                                                   int nbuck, int E) {
    __shared__ int sc[256];
    const int t = threadIdx.x;
    int v = (t < nbuck) ? ccnt[t] : 0;
    sc[t] = v;
    __syncthreads();
    for (int o = 1; o < 256; o <<= 1) {
        int x = (t >= o) ? sc[t - o] : 0;
        __syncthreads();
        sc[t] += x;
        __syncthreads();
    }
    int ex = sc[t] - v;
    if (t < nbuck) { cbase[t] = ex; ccur[t] = ex; }
    if (t == 255) cbase[nbuck] = E;
}

// ---------------- B3: scatter edges into coarse buckets (packed) ----------------
__global__ __launch_bounds__(256) void coarse_scatter(const int* __restrict__ ei, int E,
                                                      int* __restrict__ ccur,
                                                      unsigned int* __restrict__ inter) {
    __shared__ int hist[256], base[256], cur[256];
    const int t = threadIdx.x;
    hist[t] = 0; cur[t] = 0;
    __syncthreads();
    int blkbase = blockIdx.x * EPB;
    int dst[16];
#pragma unroll
    for (int i = 0; i < 16; ++i) {
        int e = blkbase + t + i * 256;
        dst[i] = -1;
        if (e < E) {
            dst[i] = ei[E + e];
            atomicAdd(&hist[dst[i] >> 8], 1);
        }
    }
    __syncthreads();
    if (hist[t]) base[t] = atomicAdd(&ccur[t], hist[t]);
    __syncthreads();
#pragma unroll
    for (int i = 0; i < 16; ++i) {
        int e = blkbase + t + i * 256;
        if (dst[i] >= 0) {
            int src = ei[e];
            int bin = dst[i] >> 8;
            int r = atomicAdd(&cur[bin], 1);
            inter[base[bin] + r] = ((unsigned int)src << 8) | (unsigned int)(dst[i] & 255);
        }
    }
}

// ---------------- B4: per-bucket finalize: rowptr, dinv, csr, srcw ----------------
__global__ __launch_bounds__(256) void bucket_build(const unsigned int* __restrict__ inter,
                                                    const int* __restrict__ cbase,
                                                    int N, ushort* __restrict__ csr,
                                                    int* __restrict__ rowptr,
                                                    float* __restrict__ dinv,
                                                    float* __restrict__ srcw) {
    __shared__ int hist[256], excl[256], cur[256], sc[256];
    __shared__ float dsh[256];
    const int b = blockIdx.x, t = threadIdx.x;
    const int lo = cbase[b], hi = cbase[b + 1], n = hi - lo;

    hist[t] = 0; cur[t] = 0;
    __syncthreads();
    for (int i = t; i < n; i += 256) atomicAdd(&hist[inter[lo + i] & 255], 1);
    __syncthreads();
    int v = hist[t];
    sc[t] = v;
    __syncthreads();
    for (int o = 1; o < 256; o <<= 1) {
        int x = (t >= o) ? sc[t - o] : 0;
        __syncthreads();
        sc[t] += x;
        __syncthreads();
    }
    int ex = sc[t] - v;
    excl[t] = ex;
    dsh[t] = rsqrtf((float)v + 1.0f);
    int node = b * 256 + t;
    if (node < N) {
        rowptr[node] = lo + ex;
        dinv[node] = dsh[t];
        if (node == N - 1) rowptr[N] = hi;
    }
    __syncthreads();
    for (int i = t; i < n; i += 256) {
        unsigned int pv = inter[lo + i];
        int low = pv & 255;
        int src = pv >> 8;
        int r = atomicAdd(&cur[low], 1);
        csr[lo + excl[low] + r] = (ushort)src;
        unsafeAtomicAdd(&srcw[src], dsh[low]);   // fire-and-forget
    }
}

// ---------------- weight prep: Wt[c][k] = (fp16) W[k][c], for W1,W2 ----------------
__global__ __launch_bounds__(128) void wprep(const float* __restrict__ W1,
                                             const float* __restrict__ W2,
                                             __half* __restrict__ Wt1,
                                             __half* __restrict__ Wt2) {
    const float* W = blockIdx.y ? W2 : W1;
    __half* Wt = blockIdx.y ? Wt2 : Wt1;
    int c = blockIdx.x, k = threadIdx.x;
    Wt[c * 128 + k] = __float2half(W[k * 128 + c]);
}

// ---------------- MFMA GEMM: T[M x 128] = A[M x 128] @ W, fp16 out ----------------
template<bool AF32>
__global__ __launch_bounds__(256) void gemm_mfma(const void* __restrict__ Aptr,
                                                 const __half* __restrict__ Wt,
                                                 ushort* __restrict__ T, int M) {
    __shared__ _Float16 Wsh[128 * 128];   // 32 KB, XOR-swizzled
    const int t = threadIdx.x;

    const float4* Wg4 = (const float4*)Wt;
    float4* Ws4 = (float4*)Wsh;
#pragma unroll
    for (int i = 0; i < 8; ++i) {
        int idx = t + i * 256;
        int row = idx >> 4;
        Ws4[(idx & ~15) | ((idx ^ row) & 7) | (idx & 8)] = Wg4[idx];
    }

    const int wave = t >> 6, lane = t & 63;
    const int row0 = blockIdx.x * 64 + wave * 16;
    const int lr = lane & 15;
    const int lk = lane >> 4;

    half8 afrag[4];
    {
        int gr = row0 + lr; if (gr >= M) gr = M - 1;
        if (AF32) {
            const float* A = (const float*)Aptr;
            const float* ap = A + (size_t)gr * 128 + lk * 8;
#pragma unroll
            for (int ks = 0; ks < 4; ++ks) {
                float4 v0 = *(const float4*)(ap + ks * 32);
                float4 v1 = *(const float4*)(ap + ks * 32 + 4);
                half8 a;
                a[0] = (_Float16)v0.x; a[1] = (_Float16)v0.y; a[2] = (_Float16)v0.z; a[3] = (_Float16)v0.w;
                a[4] = (_Float16)v1.x; a[5] = (_Float16)v1.y; a[6] = (_Float16)v1.z; a[7] = (_Float16)v1.w;
                afrag[ks] = a;
            }
        } else {
            const _Float16* A = (const _Float16*)Aptr;
            const _Float16* ap = A + (size_t)gr * 128 + lk * 8;
#pragma unroll
            for (int ks = 0; ks < 4; ++ks) afrag[ks] = *(const half8*)(ap + ks * 32);
        }
    }

    __syncthreads();

    float4v acc[8];
#pragma unroll
    for (int n = 0; n < 8; ++n) acc[n] = (float4v)0.f;

#pragma unroll
    for (int n = 0; n < 8; ++n) {
        int brow = n * 16 + lr;
#pragma unroll
        for (int ks = 0; ks < 4; ++ks) {
            int f4 = ks * 4 + lk;
            int swz = (f4 & 8) | ((f4 ^ brow) & 7);
            half8 bfr = *(const half8*)(Wsh + (size_t)brow * 128 + swz * 8);
            acc[n] = __builtin_amdgcn_mfma_f32_16x16x32_f16(afrag[ks], bfr, acc[n], 0, 0, 0);
        }
    }

#pragma unroll
    for (int n = 0; n < 8; ++n) {
#pragma unroll
        for (int r = 0; r < 4; ++r) {
            int gr = row0 + lk * 4 + r;
            if (gr < M) {
                __half hv = __float2half(acc[n][r]);
                T[(size_t)gr * 128 + n * 16 + lr] = *(const ushort*)&hv;
            }
        }
    }
}

// ---------------- CSR aggregate (fp16 gather, f32 accum), fp16 out ----------------
__global__ __launch_bounds__(256) void agg_kernel(const int* __restrict__ rowptr,
                                                  const ushort* __restrict__ csr,
                                                  const __half2* __restrict__ t2,
                                                  const float* __restrict__ dinv,
                                                  const float* __restrict__ b,
                                                  __half2* __restrict__ h, int N) {
    int tid = blockIdx.x * 256 + threadIdx.x;
    int node = tid >> 6;
    if (node >= N) return;
    int lane = tid & 63;
    int beg = rowptr[node];
    int end = rowptr[node + 1];

    float di = dinv[node];
    float2 tv = __half22float2(t2[(size_t)node * 64 + lane]);
    float2 acc = make_float2(di * tv.x, di * tv.y);

    for (int k0 = beg; k0 < end; k0 += 16) {
        int cn = end - k0; if (cn > 16) cn = 16;
        int s = 0; float w = 0.f;
        if (lane < 16 && lane < cn) { s = csr[k0 + lane]; w = dinv[s]; }
        if (cn == 16) {
#pragma unroll
            for (int j = 0; j < 16; ++j) {
                int sj = __shfl(s, j);
                float wj = __shfl(w, j);
                float2 v = __half22float2(t2[(size_t)sj * 64 + lane]);
                acc.x = fmaf(v.x, wj, acc.x);
                acc.y = fmaf(v.y, wj, acc.y);
            }
        } else {
            for (int j = 0; j < cn; ++j) {
                int sj = __shfl(s, j);
                float wj = __shfl(w, j);
                float2 v = __half22float2(t2[(size_t)sj * 64 + lane]);
                acc.x = fmaf(v.x, wj, acc.x);
                acc.y = fmaf(v.y, wj, acc.y);
            }
        }
    }

    float2 bv = ((const float2*)b)[lane];
    acc.x = fmaxf(fmaf(acc.x, di, bv.x), 0.f);
    acc.y = fmaxf(fmaf(acc.y, di, bv.y), 0.f);
    h[(size_t)node * 64 + lane] = __floats2half2_rn(acc.x, acc.y);
}

// ---------------- weighted row-sum over fp16 h ----------------
__global__ __launch_bounds__(128) void wreduce(const __half* __restrict__ h,
                                               const float* __restrict__ dinv,
                                               const float* __restrict__ srcw,
                                               float* __restrict__ v, int N, int npb) {
    int c = threadIdx.x;
    int i0 = blockIdx.x * npb;
    int i1 = min(i0 + npb, N);
    float s = 0.f;
    for (int i = i0; i < i1; ++i) {
        float di = dinv[i];
        float w = di * (di + srcw[i]);
        s = fmaf(__half2float(h[(size_t)i * C + c]), w, s);
    }
    unsafeAtomicAdd(&v[c], s);
}

// ---------------- out = (v @ W3)/N + b3 ----------------
__global__ __launch_bounds__(128) void matvec(const float* __restrict__ v,
                                              const float* __restrict__ W,
                                              const float* __restrict__ b,
                                              float* __restrict__ out, float invN) {
    int c = threadIdx.x;
    float s = 0.f;
    for (int k = 0; k < C; ++k) s = fmaf(v[k], W[(size_t)k * C + c], s);
    out[c] = s * invN + b[c];
}

extern "C" void kernel_launch(void* const* d_in, const int* in_sizes, int n_in,
                              void* d_out, int out_size, void* d_ws, size_t ws_size,
                              hipStream_t stream) {
    const float* x  = (const float*)d_in[0];
    const int*   ei = (const int*)d_in[1];
    const float* W1 = (const float*)d_in[2];
    const float* b1 = (const float*)d_in[3];
    const float* W2 = (const float*)d_in[4];
    const float* b2 = (const float*)d_in[5];
    const float* W3 = (const float*)d_in[6];
    const float* b3 = (const float*)d_in[7];
    float* out = (float*)d_out;

    const int N = in_sizes[0] / C;      // 50000 (< 65536)
    const int E = in_sizes[1] / 2;      // 800000

    char* ws = (char*)d_ws;
    size_t off = 0;
    auto alloc = [&](size_t bytes) { char* p = ws + off; off += (bytes + 255) & ~(size_t)255; return p; };
    ushort* tbuf   = (ushort*)alloc((size_t)N * C * sizeof(ushort));  // t (fp16)
    ushort* hbuf   = (ushort*)alloc((size_t)N * C * sizeof(ushort));  // h (fp16)
    unsigned int* inter = (unsigned int*)alloc((size_t)E * sizeof(unsigned int)); // 3.2 MB
    ushort* csr    = (ushort*)alloc((size_t)E * sizeof(ushort));
    int*    rowptr = (int*)alloc((size_t)(N + 1) * sizeof(int));
    float*  dinv   = (float*)alloc((size_t)N * sizeof(float));
    float*  srcw   = (float*)alloc((size_t)N * sizeof(float));
    float*  vsum   = (float*)alloc((size_t)C * sizeof(float));
    int*    ccnt   = (int*)alloc(257 * sizeof(int));
    int*    cbase  = (int*)alloc(257 * sizeof(int));
    int*    ccur   = (int*)alloc(257 * sizeof(int));
    __half* Wt1    = (__half*)alloc((size_t)C * C * sizeof(__half));
    __half* Wt2    = (__half*)alloc((size_t)C * C * sizeof(__half));

    hipMemsetAsync(ccnt, 0, 257 * sizeof(int), stream);
    hipMemsetAsync(srcw, 0, (size_t)N * sizeof(float), stream);
    hipMemsetAsync(vsum, 0, (size_t)C * sizeof(float), stream);

    const int nbuck = (N + 255) >> 8;           // 196
    const int nbB = (E + EPB - 1) / EPB;        // 196

    coarse_hist<<<nbB, 256, 0, stream>>>(ei, E, ccnt);
    scan_coarse<<<1, 256, 0, stream>>>(ccnt, cbase, ccur, nbuck, E);
    coarse_scatter<<<nbB, 256, 0, stream>>>(ei, E, ccur, inter);
    bucket_build<<<nbuck, 256, 0, stream>>>(inter, cbase, N, csr, rowptr, dinv, srcw);
    wprep<<<dim3(128, 2), 128, 0, stream>>>(W1, W2, Wt1, Wt2);

    const int gb = (N + 63) / 64;
    const int ab = (int)(((long long)N * 64 + 255) / 256);
    const int rb = 391;
    const int npb = (N + rb - 1) / rb;

    // layer 1
    gemm_mfma<true><<<gb, 256, 0, stream>>>(x, Wt1, tbuf, N);
    agg_kernel<<<ab, 256, 0, stream>>>(rowptr, csr, (const __half2*)tbuf, dinv, b1, (__half2*)hbuf, N);
    // layer 2
    gemm_mfma<false><<<gb, 256, 0, stream>>>(hbuf, Wt2, tbuf, N);
    agg_kernel<<<ab, 256, 0, stream>>>(rowptr, csr, (const __half2*)tbuf, dinv, b2, (__half2*)hbuf, N);
    // layer 3 collapsed
    wreduce<<<rb, 128, 0, stream>>>((const __half*)hbuf, dinv, srcw, vsum, N, npb);
    matvec<<<1, 128, 0, stream>>>(vsum, W3, b3, out, 1.0f / (float)N);
}

// Round 8
// 225.577 us; speedup vs baseline: 9.9279x; 1.0622x over previous
//
#include <hip/hip_runtime.h>
#include <hip/hip_bf16.h>
#include <hip/hip_fp16.h>

// GCN 3-layer embedder. CSR via two-level counting sort (1024-thr blocks).
// GEMM epilogue scales rows by dinv: u = dinv.*(A@W) stored fp16, so
//   Agg(t)[i] = dinv_i * ( sum_{e: dst=i} u[src_e] + u[i] )   (unweighted gather!)
// Layer 3 + mean collapsed:
//   out = ((sum_i w_i * h2[i]) @ W3)/N + b3,  w_i = dinv_i^2 + dinv_i * sum_{e:src=i} dinv[dst_e]

#define C 128
#define EPB 4096   // edges per block in binning kernels

typedef __attribute__((ext_vector_type(8))) _Float16 half8;
typedef __attribute__((ext_vector_type(4))) float float4v;

// ---------------- B1: coarse histogram of dst>>8 ----------------
__global__ __launch_bounds__(1024) void coarse_hist(const int* __restrict__ ei, int E,
                                                    int* __restrict__ ccnt) {
    __shared__ int hist[4][256];
    const int t = threadIdx.x, grp = t >> 8;
    if (t < 256) { hist[0][t] = 0; hist[1][t] = 0; hist[2][t] = 0; hist[3][t] = 0; }
    __syncthreads();
    int blk = blockIdx.x * EPB;
#pragma unroll
    for (int i = 0; i < 4; ++i) {
        int e = blk + t + i * 1024;
        if (e < E) atomicAdd(&hist[grp][ei[E + e] >> 8], 1);
    }
    __syncthreads();
    if (t < 256) {
        int s = hist[0][t] + hist[1][t] + hist[2][t] + hist[3][t];
        if (s) atomicAdd(&ccnt[t], s);
    }
}

// ---------------- B2: exclusive scan of coarse counts ----------------
__global__ __launch_bounds__(256) void scan_coarse(const int* __restrict__ ccnt,
                                                   int* __restrict__ cbase,
                                                   int* __restrict__ ccur,
                                                   int nbuck, int E) {
    __shared__ int sc[256];
    const int t = threadIdx.x;
    int v = (t < nbuck) ? ccnt[t] : 0;
    sc[t] = v;
    __syncthreads();
    for (int o = 1; o < 256; o <<= 1) {
        int x = (t >= o) ? sc[t - o] : 0;
        __syncthreads();
        sc[t] += x;
        __syncthreads();
    }
    int ex = sc[t] - v;
    if (t < nbuck) { cbase[t] = ex; ccur[t] = ex; }
    if (t == 255) cbase[nbuck] = E;
}

// ---------------- B3: scatter edges into coarse buckets (packed src<<8|dst&255) ----------------
__global__ __launch_bounds__(1024) void coarse_scatter(const int* __restrict__ ei, int E,
                                                       int* __restrict__ ccur,
                                                       unsigned int* __restrict__ inter) {
    __shared__ int hist[4][256];
    __shared__ int base[256], cur[256];
    const int t = threadIdx.x, grp = t >> 8;
    if (t < 256) { hist[0][t] = 0; hist[1][t] = 0; hist[2][t] = 0; hist[3][t] = 0; cur[t] = 0; }
    __syncthreads();
    int blk = blockIdx.x * EPB;
    int dst[4], src[4];
#pragma unroll
    for (int i = 0; i < 4; ++i) {
        int e = blk + t + i * 1024;
        dst[i] = -1;
        if (e < E) {
            dst[i] = ei[E + e];
            src[i] = ei[e];
            atomicAdd(&hist[grp][dst[i] >> 8], 1);
        }
    }
    __syncthreads();
    if (t < 256) {
        int hsum = hist[0][t] + hist[1][t] + hist[2][t] + hist[3][t];
        if (hsum) base[t] = atomicAdd(&ccur[t], hsum) - 0;
    }
    __syncthreads();
#pragma unroll
    for (int i = 0; i < 4; ++i) {
        if (dst[i] >= 0) {
            int bin = dst[i] >> 8;
            int r = atomicAdd(&cur[bin], 1);
            inter[base[bin] + r] = ((unsigned int)src[i] << 8) | (unsigned int)(dst[i] & 255);
        }
    }
}

// ---------------- B4: per-bucket finalize: rowptr, dinv, csr, srcw ----------------
__global__ __launch_bounds__(1024) void bucket_build(const unsigned int* __restrict__ inter,
                                                     const int* __restrict__ cbase,
                                                     int N, ushort* __restrict__ csr,
                                                     int* __restrict__ rowptr,
                                                     float* __restrict__ dinv,
                                                     float* __restrict__ srcw) {
    __shared__ int hist[4][256];
    __shared__ int excl[256], cur[256], sc[256];
    __shared__ float dsh[256];
    const int b = blockIdx.x, t = threadIdx.x, grp = t >> 8;
    const int lo = cbase[b], hi = cbase[b + 1], n = hi - lo;

    if (t < 256) { hist[0][t] = 0; hist[1][t] = 0; hist[2][t] = 0; hist[3][t] = 0; cur[t] = 0; }
    __syncthreads();
    for (int i = t; i < n; i += 1024) atomicAdd(&hist[grp][inter[lo + i] & 255], 1);
    __syncthreads();
    int v = 0;
    if (t < 256) { v = hist[0][t] + hist[1][t] + hist[2][t] + hist[3][t]; sc[t] = v; }
    __syncthreads();
    for (int o = 1; o < 256; o <<= 1) {
        int x = 0;
        if (t < 256 && t >= o) x = sc[t - o];
        __syncthreads();
        if (t < 256) sc[t] += x;
        __syncthreads();
    }
    if (t < 256) {
        int ex = sc[t] - v;
        excl[t] = ex;
        float dv = rsqrtf((float)v + 1.0f);
        dsh[t] = dv;
        int node = b * 256 + t;
        if (node < N) {
            rowptr[node] = lo + ex;
            dinv[node] = dv;
            if (node == N - 1) rowptr[N] = hi;
        }
    }
    __syncthreads();
    for (int i = t; i < n; i += 1024) {
        unsigned int pv = inter[lo + i];
        int low = pv & 255;
        int src = pv >> 8;
        int r = atomicAdd(&cur[low], 1);
        csr[lo + excl[low] + r] = (ushort)src;
        unsafeAtomicAdd(&srcw[src], dsh[low]);   // fire-and-forget
    }
}

// ---------------- weight prep: Wt[c][k] = (fp16) W[k][c], for W1,W2 ----------------
__global__ __launch_bounds__(128) void wprep(const float* __restrict__ W1,
                                             const float* __restrict__ W2,
                                             __half* __restrict__ Wt1,
                                             __half* __restrict__ Wt2) {
    const float* W = blockIdx.y ? W2 : W1;
    __half* Wt = blockIdx.y ? Wt2 : Wt1;
    int c = blockIdx.x, k = threadIdx.x;
    Wt[c * 128 + k] = __float2half(W[k * 128 + c]);
}

// ---------------- MFMA GEMM: U[M x 128] = dinv .* (A[M x 128] @ W), fp16 out ----------------
template<bool AF32>
__global__ __launch_bounds__(256) void gemm_mfma(const void* __restrict__ Aptr,
                                                 const __half* __restrict__ Wt,
                                                 const float* __restrict__ dinv,
                                                 ushort* __restrict__ U, int M) {
    __shared__ _Float16 Wsh[128 * 128];   // 32 KB, XOR-swizzled
    const int t = threadIdx.x;

    const float4* Wg4 = (const float4*)Wt;
    float4* Ws4 = (float4*)Wsh;
#pragma unroll
    for (int i = 0; i < 8; ++i) {
        int idx = t + i * 256;
        int row = idx >> 4;
        Ws4[(idx & ~15) | ((idx ^ row) & 7) | (idx & 8)] = Wg4[idx];
    }

    const int wave = t >> 6, lane = t & 63;
    const int row0 = blockIdx.x * 64 + wave * 16;
    const int lr = lane & 15;
    const int lk = lane >> 4;

    half8 afrag[4];
    {
        int gr = row0 + lr; if (gr >= M) gr = M - 1;
        if (AF32) {
            const float* A = (const float*)Aptr;
            const float* ap = A + (size_t)gr * 128 + lk * 8;
#pragma unroll
            for (int ks = 0; ks < 4; ++ks) {
                float4 v0 = *(const float4*)(ap + ks * 32);
                float4 v1 = *(const float4*)(ap + ks * 32 + 4);
                half8 a;
                a[0] = (_Float16)v0.x; a[1] = (_Float16)v0.y; a[2] = (_Float16)v0.z; a[3] = (_Float16)v0.w;
                a[4] = (_Float16)v1.x; a[5] = (_Float16)v1.y; a[6] = (_Float16)v1.z; a[7] = (_Float16)v1.w;
                afrag[ks] = a;
            }
        } else {
            const _Float16* A = (const _Float16*)Aptr;
            const _Float16* ap = A + (size_t)gr * 128 + lk * 8;
#pragma unroll
            for (int ks = 0; ks < 4; ++ks) afrag[ks] = *(const half8*)(ap + ks * 32);
        }
    }

    __syncthreads();

    float4v acc[8];
#pragma unroll
    for (int n = 0; n < 8; ++n) acc[n] = (float4v)0.f;

#pragma unroll
    for (int n = 0; n < 8; ++n) {
        int brow = n * 16 + lr;
#pragma unroll
        for (int ks = 0; ks < 4; ++ks) {
            int f4 = ks * 4 + lk;
            int swz = (f4 & 8) | ((f4 ^ brow) & 7);
            half8 bfr = *(const half8*)(Wsh + (size_t)brow * 128 + swz * 8);
            acc[n] = __builtin_amdgcn_mfma_f32_16x16x32_f16(afrag[ks], bfr, acc[n], 0, 0, 0);
        }
    }

    float dv[4];
#pragma unroll
    for (int r = 0; r < 4; ++r) {
        int gr = row0 + lk * 4 + r;
        dv[r] = (gr < M) ? dinv[gr] : 0.f;
    }
#pragma unroll
    for (int n = 0; n < 8; ++n) {
#pragma unroll
        for (int r = 0; r < 4; ++r) {
            int gr = row0 + lk * 4 + r;
            if (gr < M) {
                __half hv = __float2half(acc[n][r] * dv[r]);
                U[(size_t)gr * 128 + n * 16 + lr] = *(const ushort*)&hv;
            }
        }
    }
}

// ---------------- CSR aggregate: h = relu(dinv_i*(sum u[src] + u[i]) + b), fp16 out ----------------
// One wave per dst node. lane = 4 channels (8B half4); halves of the wave take
// alternate edges (2 rows in flight per instruction); shfl_xor(32) reduce at end.
__global__ __launch_bounds__(256) void agg_kernel(const int* __restrict__ rowptr,
                                                  const ushort* __restrict__ csr,
                                                  const uint2* __restrict__ u,   // row = 32 uint2
                                                  const float* __restrict__ dinv,
                                                  const float* __restrict__ b,
                                                  uint2* __restrict__ h, int N) {
    int tid = blockIdx.x * 256 + threadIdx.x;
    int node = tid >> 6;
    if (node >= N) return;
    int lane = tid & 63;
    int c4 = lane & 31;          // half4 index within row
    int hf = lane >> 5;          // 0: even edges, 1: odd edges
    int beg = rowptr[node];
    int end = rowptr[node + 1];

    float4 acc = make_float4(0.f, 0.f, 0.f, 0.f);
    if (hf == 0) {               // self-loop term u[node] (counted once)
        uint2 uv = u[(size_t)node * 32 + c4];
        float2 f0 = __half22float2(*(__half2*)&uv.x);
        float2 f1 = __half22float2(*(__half2*)&uv.y);
        acc = make_float4(f0.x, f0.y, f1.x, f1.y);
    }

    for (int k0 = beg; k0 < end; k0 += 16) {
        int cn = end - k0; if (cn > 16) cn = 16;
        int s = (lane < cn) ? (int)csr[k0 + lane] : 0;   // lanes 0..cn-1 hold entries
        if (cn == 16) {
#pragma unroll
            for (int j = 0; j < 16; j += 2) {
                int sj0 = __shfl(s, j);
                int sj1 = __shfl(s, j + 1);
                int sj = hf ? sj1 : sj0;
                uint2 uv = u[(size_t)sj * 32 + c4];
                float2 f0 = __half22float2(*(__half2*)&uv.x);
                float2 f1 = __half22float2(*(__half2*)&uv.y);
                acc.x += f0.x; acc.y += f0.y; acc.z += f1.x; acc.w += f1.y;
            }
        } else {
            int pairs = cn & ~1;
            for (int j = 0; j < pairs; j += 2) {
                int sj0 = __shfl(s, j);
                int sj1 = __shfl(s, j + 1);
                int sj = hf ? sj1 : sj0;
                uint2 uv = u[(size_t)sj * 32 + c4];
                float2 f0 = __half22float2(*(__half2*)&uv.x);
                float2 f1 = __half22float2(*(__half2*)&uv.y);
                acc.x += f0.x; acc.y += f0.y; acc.z += f1.x; acc.w += f1.y;
            }
            if (cn & 1) {
                int sj = __shfl(s, cn - 1);
                if (!hf) {
                    uint2 uv = u[(size_t)sj * 32 + c4];
                    float2 f0 = __half22float2(*(__half2*)&uv.x);
                    float2 f1 = __half22float2(*(__half2*)&uv.y);
                    acc.x += f0.x; acc.y += f0.y; acc.z += f1.x; acc.w += f1.y;
                }
            }
        }
    }

    // combine halves
    acc.x += __shfl_xor(acc.x, 32);
    acc.y += __shfl_xor(acc.y, 32);
    acc.z += __shfl_xor(acc.z, 32);
    acc.w += __shfl_xor(acc.w, 32);

    if (hf == 0) {
        float di = dinv[node];
        float4 bv = ((const float4*)b)[c4];
        float4 r;
        r.x = fmaxf(fmaf(acc.x, di, bv.x), 0.f);
        r.y = fmaxf(fmaf(acc.y, di, bv.y), 0.f);
        r.z = fmaxf(fmaf(acc.z, di, bv.z), 0.f);
        r.w = fmaxf(fmaf(acc.w, di, bv.w), 0.f);
        __half2 p0 = __floats2half2_rn(r.x, r.y);
        __half2 p1 = __floats2half2_rn(r.z, r.w);
        uint2 o;
        o.x = *(const unsigned int*)&p0;
        o.y = *(const unsigned int*)&p1;
        h[(size_t)node * 32 + c4] = o;
    }
}

// ---------------- weighted row-sum over fp16 h ----------------
__global__ __launch_bounds__(128) void wreduce(const __half* __restrict__ h,
                                               const float* __restrict__ dinv,
                                               const float* __restrict__ srcw,
                                               float* __restrict__ v, int N, int npb) {
    int c = threadIdx.x;
    int i0 = blockIdx.x * npb;
    int i1 = min(i0 + npb, N);
    float s = 0.f;
    for (int i = i0; i < i1; ++i) {
        float di = dinv[i];
        float w = di * (di + srcw[i]);
        s = fmaf(__half2float(h[(size_t)i * C + c]), w, s);
    }
    unsafeAtomicAdd(&v[c], s);
}

// ---------------- out = (v @ W3)/N + b3 ----------------
__global__ __launch_bounds__(128) void matvec(const float* __restrict__ v,
                                              const float* __restrict__ W,
                                              const float* __restrict__ b,
                                              float* __restrict__ out, float invN) {
    int c = threadIdx.x;
    float s = 0.f;
    for (int k = 0; k < C; ++k) s = fmaf(v[k], W[(size_t)k * C + c], s);
    out[c] = s * invN + b[c];
}

extern "C" void kernel_launch(void* const* d_in, const int* in_sizes, int n_in,
                              void* d_out, int out_size, void* d_ws, size_t ws_size,
                              hipStream_t stream) {
    const float* x  = (const float*)d_in[0];
    const int*   ei = (const int*)d_in[1];
    const float* W1 = (const float*)d_in[2];
    const float* b1 = (const float*)d_in[3];
    const float* W2 = (const float*)d_in[4];
    const float* b2 = (const float*)d_in[5];
    const float* W3 = (const float*)d_in[6];
    const float* b3 = (const float*)d_in[7];
    float* out = (float*)d_out;

    const int N = in_sizes[0] / C;      // 50000 (< 65536)
    const int E = in_sizes[1] / 2;      // 800000

    char* ws = (char*)d_ws;
    size_t off = 0;
    auto alloc = [&](size_t bytes) { char* p = ws + off; off += (bytes + 255) & ~(size_t)255; return p; };
    ushort* ubuf   = (ushort*)alloc((size_t)N * C * sizeof(ushort));  // u = dinv.*(A@W) fp16
    ushort* hbuf   = (ushort*)alloc((size_t)N * C * sizeof(ushort));  // h fp16
    unsigned int* inter = (unsigned int*)alloc((size_t)E * sizeof(unsigned int));
    ushort* csr    = (ushort*)alloc((size_t)E * sizeof(ushort));
    int*    rowptr = (int*)alloc((size_t)(N + 1) * sizeof(int));
    float*  dinv   = (float*)alloc((size_t)N * sizeof(float));
    float*  srcw   = (float*)alloc((size_t)N * sizeof(float));
    float*  vsum   = (float*)alloc((size_t)C * sizeof(float));
    int*    ccnt   = (int*)alloc(257 * sizeof(int));
    int*    cbase  = (int*)alloc(257 * sizeof(int));
    int*    ccur   = (int*)alloc(257 * sizeof(int));
    __half* Wt1    = (__half*)alloc((size_t)C * C * sizeof(__half));
    __half* Wt2    = (__half*)alloc((size_t)C * C * sizeof(__half));

    hipMemsetAsync(ccnt, 0, 257 * sizeof(int), stream);
    hipMemsetAsync(srcw, 0, (size_t)N * sizeof(float), stream);
    hipMemsetAsync(vsum, 0, (size_t)C * sizeof(float), stream);

    const int nbuck = (N + 255) >> 8;           // 196
    const int nbB = (E + EPB - 1) / EPB;        // 196

    coarse_hist<<<nbB, 1024, 0, stream>>>(ei, E, ccnt);
    scan_coarse<<<1, 256, 0, stream>>>(ccnt, cbase, ccur, nbuck, E);
    coarse_scatter<<<nbB, 1024, 0, stream>>>(ei, E, ccur, inter);
    bucket_build<<<nbuck, 1024, 0, stream>>>(inter, cbase, N, csr, rowptr, dinv, srcw);
    wprep<<<dim3(128, 2), 128, 0, stream>>>(W1, W2, Wt1, Wt2);

    const int gb = (N + 63) / 64;
    const int ab = (int)(((long long)N * 64 + 255) / 256);
    const int rb = 391;
    const int npb = (N + rb - 1) / rb;

    // layer 1
    gemm_mfma<true><<<gb, 256, 0, stream>>>(x, Wt1, dinv, ubuf, N);
    agg_kernel<<<ab, 256, 0, stream>>>(rowptr, csr, (const uint2*)ubuf, dinv, b1, (uint2*)hbuf, N);
    // layer 2
    gemm_mfma<false><<<gb, 256, 0, stream>>>(hbuf, Wt2, dinv, ubuf, N);
    agg_kernel<<<ab, 256, 0, stream>>>(rowptr, csr, (const uint2*)ubuf, dinv, b2, (uint2*)hbuf, N);
    // layer 3 collapsed
    wreduce<<<rb, 128, 0, stream>>>((const __half*)hbuf, dinv, srcw, vsum, N, npb);
    matvec<<<1, 128, 0, stream>>>(vsum, W3, b3, out, 1.0f / (float)N);
}